// Round 5
// baseline (730.490 us; speedup 1.0000x reference)
//
#include <hip/hip_runtime.h>
#include <math.h>

#define NEG_SLOPE 0.01f

__device__ __forceinline__ float lrelu_f(float x) { return x >= 0.f ? x : NEG_SLOPE * x; }

// ---------------------------------------------------------------------------
// GEMM: C[m][n] = act( sum_k A[m][k] * B[n][k] (+ bias[n]) )
// A: [M][K] row-major, B: [N][K] row-major (C = A @ B^T), all fp32.
// Tile: 128 rows x TN cols (TN in {64,128}), K-chunk 64, 256 threads,
// 8 x (TN/16) acc per thread. Requires N%TN==0, K%64==0. M arbitrary
// (A loads clamp to M-1, C stores predicated).
//
// TN=128: LDS 66KB -> 2 blocks/CU. TN=64: LDS 51KB -> 3 blocks/CU; used for
// narrow N (128, 384) where a 128-wide tile under-subscribes the grid
// (313 blocks on 256 CUs = 1 wave/SIMD = exposed LDS latency + barriers).
//
// LDS layout: transposed [k][m], row stride TN+4 words, 4-word-granular XOR
// column swizzle: word' = word ^ ((k>>2 & 15) << 2). Un-swizzled, staging
// writes are 8-way bank-conflicted (~2.94x, m136); swizzled they spread to
// 2 lanes/bank (free). Reads use the same key per kk: A-reads stay 16-lane
// broadcasts (free); B-reads: TN=128 4-way (1.58x), TN=64 2-way (free).
// All float4 LDS addresses stay 16B-aligned (keys live in word bits 2-5).
// ---------------------------------------------------------------------------
template<int TN, bool LRELU, bool BIAS>
__global__ __launch_bounds__(256)
void gemm_nt(const float* __restrict__ A, const float* __restrict__ B,
             const float* __restrict__ bias, float* __restrict__ C,
             int M, int Nn, int K) {
  constexpr int SB = TN + 4;       // Bs row stride (words)
  constexpr int CN = TN / 16;      // cols per thread (4 or 8)
  __shared__ float As[64 * 132];   // [k][m'] transposed + swizzled
  __shared__ float Bs[64 * SB];    // [k][n']
  const int tid = threadIdx.x;
  const int tx = tid & 15, ty = tid >> 4;
  const int bm = blockIdx.y << 7, bn = blockIdx.x * TN;
  const int tcol = tx << 2;        // k-offset 0..60
  const int trow = ty;             // 0..15
  const int wkey = tx << 2;        // write swizzle key ((k>>2)&15)<<2, k=tcol+c
  float acc[8][CN];
#pragma unroll
  for (int i = 0; i < 8; ++i)
#pragma unroll
    for (int j = 0; j < CN; ++j) acc[i][j] = 0.f;

  for (int k0 = 0; k0 < K; k0 += 64) {
#pragma unroll
    for (int i = 0; i < 8; ++i) {                 // stage A (128 rows)
      const int r = trow + (i << 4);
      int ar = bm + r; ar = ar < M ? ar : M - 1;  // clamp (predicated at store)
      const float4 va = *(const float4*)(A + (size_t)ar * K + k0 + tcol);
      const int rw = r ^ wkey;
      As[(tcol + 0) * 132 + rw] = va.x; As[(tcol + 1) * 132 + rw] = va.y;
      As[(tcol + 2) * 132 + rw] = va.z; As[(tcol + 3) * 132 + rw] = va.w;
    }
#pragma unroll
    for (int i = 0; i < TN / 16; ++i) {           // stage B (TN rows)
      const int r = trow + (i << 4);
      const float4 vb = *(const float4*)(B + (size_t)(bn + r) * K + k0 + tcol);
      const int rw = r ^ wkey;
      Bs[(tcol + 0) * SB + rw] = vb.x; Bs[(tcol + 1) * SB + rw] = vb.y;
      Bs[(tcol + 2) * SB + rw] = vb.z; Bs[(tcol + 3) * SB + rw] = vb.w;
    }
    __syncthreads();
    for (int kk4 = 0; kk4 < 64; kk4 += 4) {
      const int kxor = kk4;        // ((kk>>2)&15)<<2 == kk4 for kk in [kk4,kk4+4)
#pragma unroll
      for (int c = 0; c < 4; ++c) {
        const float* arow = As + (kk4 + c) * 132;
        const float* brow = Bs + (kk4 + c) * SB;
        const float4 a0 = *(const float4*)(arow + ((ty << 3) ^ kxor));
        const float4 a1 = *(const float4*)(arow + (((ty << 3) + 4) ^ kxor));
        const float av[8] = {a0.x, a0.y, a0.z, a0.w, a1.x, a1.y, a1.z, a1.w};
        float bv[CN];
        {
          const float4 b0 = *(const float4*)(brow + ((tx * CN) ^ kxor));
          bv[0] = b0.x; bv[1] = b0.y; bv[2] = b0.z; bv[3] = b0.w;
          if (CN == 8) {
            const float4 b1 = *(const float4*)(brow + ((tx * CN + 4) ^ kxor));
            bv[4] = b1.x; bv[5] = b1.y; bv[6] = b1.z; bv[7] = b1.w;
          }
        }
#pragma unroll
        for (int i = 0; i < 8; ++i)
#pragma unroll
          for (int j = 0; j < CN; ++j) acc[i][j] = fmaf(av[i], bv[j], acc[i][j]);
      }
    }
    __syncthreads();
  }

#pragma unroll
  for (int i = 0; i < 8; ++i) {
    const int row = bm + (ty << 3) + i;
    if (row >= M) break;
    const int col = bn + tx * CN;
    float v[CN];
#pragma unroll
    for (int j = 0; j < CN; ++j) {
      v[j] = acc[i][j];
      if (BIAS) v[j] += bias[col + j];
      if (LRELU) v[j] = lrelu_f(v[j]);
    }
#pragma unroll
    for (int q = 0; q < CN; q += 4)
      *(float4*)(C + (size_t)row * Nn + col + q) = make_float4(v[q], v[q + 1], v[q + 2], v[q + 3]);
  }
}

// ---------------------------------------------------------------------------
// a_src/a_dst for the 4 heads. z: [N][512] (head h = cols h*128..h*128+127).
// One wave per node; lanes h*16..h*16+15 own head h (8 dims each).
// attnW: [4][256]. Outputs: asrc/adst [4][N].
// ---------------------------------------------------------------------------
__global__ __launch_bounds__(256)
void attn_heads_k(const float* __restrict__ z, const float* __restrict__ attnW,
                  float* __restrict__ asrc, float* __restrict__ adst, int N) {
  const int wid = (int)((blockIdx.x * (unsigned)blockDim.x + threadIdx.x) >> 6);
  const int lane = threadIdx.x & 63;
  if (wid >= N) return;
  const int h = lane >> 4;
  const int dd = (lane & 15) << 3;
  const float* zp = z + (size_t)wid * 512 + h * 128 + dd;
  const float* aw = attnW + h * 256 + dd;
  const float4 z0 = *(const float4*)zp;
  const float4 z1 = *(const float4*)(zp + 4);
  const float4 w0 = *(const float4*)aw;
  const float4 w1 = *(const float4*)(aw + 4);
  const float4 w2 = *(const float4*)(aw + 128);
  const float4 w3 = *(const float4*)(aw + 132);
  float ps = z0.x * w0.x + z0.y * w0.y + z0.z * w0.z + z0.w * w0.w
           + z1.x * w1.x + z1.y * w1.y + z1.z * w1.z + z1.w * w1.w;
  float pq = z0.x * w2.x + z0.y * w2.y + z0.z * w2.z + z0.w * w2.w
           + z1.x * w3.x + z1.y * w3.y + z1.z * w3.z + z1.w * w3.w;
#pragma unroll
  for (int off = 8; off; off >>= 1) {
    ps += __shfl_xor(ps, off);
    pq += __shfl_xor(pq, off);
  }
  if ((lane & 15) == 0) {
    asrc[(size_t)h * N + wid] = ps;
    adst[(size_t)h * N + wid] = pq;
  }
}

// a_src/a_dst for the output layer. z2: [N][128]. attnW: [256]. One wave/node.
__global__ __launch_bounds__(256)
void attn_out_k(const float* __restrict__ z2, const float* __restrict__ attnW,
                float* __restrict__ asrc, float* __restrict__ adst, int N) {
  const int wid = (int)((blockIdx.x * (unsigned)blockDim.x + threadIdx.x) >> 6);
  const int lane = threadIdx.x & 63;
  if (wid >= N) return;
  const float* zp = z2 + (size_t)wid * 128;
  const float za = zp[lane], zb = zp[lane + 64];
  float ps = za * attnW[lane] + zb * attnW[lane + 64];
  float pq = za * attnW[128 + lane] + zb * attnW[192 + lane];
#pragma unroll
  for (int off = 32; off; off >>= 1) {
    ps += __shfl_xor(ps, off);
    pq += __shfl_xor(pq, off);
  }
  if (lane == 0) {
    asrc[wid] = ps;
    adst[wid] = pq;
  }
}

// ---------------------------------------------------------------------------
// CSR build over dst. scatter_k writes dst-sorted copies of src and pd
// directly (no eidx indirection): aggregates then read edges coalesced.
// ---------------------------------------------------------------------------
__global__ void hist_k(const int* __restrict__ dst, int* __restrict__ deg, int E) {
  const int i = blockIdx.x * 256 + threadIdx.x;
  if (i < E) atomicAdd(&deg[dst[i]], 1);
}

// Single-block exclusive scan (1024 thr): ptr[0]=0, ptr[i+1]=sum(deg[0..i]).
// Wave-level shuffle scans + wave-sum scan; 4 barriers per 1024 elements.
__global__ __launch_bounds__(1024)
void scan_k(const int* __restrict__ deg, int* __restrict__ ptr, int n) {
  __shared__ int wsum[16];
  __shared__ int carry_s;
  const int tid = threadIdx.x;
  const int lane = tid & 63, wv = tid >> 6;
  if (tid == 0) carry_s = 0;
  __syncthreads();
  for (int base = 0; base < n; base += 1024) {
    const int i = base + tid;
    int s = (i < n) ? deg[i] : 0;
#pragma unroll
    for (int off = 1; off < 64; off <<= 1) {  // inclusive wave scan
      const int t = __shfl_up(s, off);
      if (lane >= off) s += t;
    }
    if (lane == 63) wsum[wv] = s;
    __syncthreads();
    if (wv == 0 && lane < 16) {               // scan the 16 wave sums
      int ws = wsum[lane];
#pragma unroll
      for (int off = 1; off < 16; off <<= 1) {
        const int t = __shfl_up(ws, off);
        if (lane >= off) ws += t;
      }
      wsum[lane] = ws;
    }
    __syncthreads();
    const int wprefix = (wv == 0) ? 0 : wsum[wv - 1];
    const int carry = carry_s;
    if (i < n) ptr[i + 1] = carry + wprefix + s;
    __syncthreads();                          // everyone done reading carry_s/wsum
    if (tid == 1023) carry_s = carry + wsum[15];
    __syncthreads();
  }
  if (tid == 0) ptr[0] = 0;
}

__global__ void scatter_k(const int* __restrict__ dst, const int* __restrict__ src,
                          const float* __restrict__ pd, const int* __restrict__ ptr,
                          int* __restrict__ cursor,
                          int* __restrict__ src_s, float* __restrict__ pd_s, int E) {
  const int i = blockIdx.x * 256 + threadIdx.x;
  if (i < E) {
    const int d = dst[i];
    const int p = ptr[d] + atomicAdd(&cursor[d], 1);
    src_s[p] = src[i];
    pd_s[p] = pd[i];
  }
}

// ---------------------------------------------------------------------------
// Segment softmax + weighted aggregation for one GAT layer.
// One wave per dst node (grid.y = head). Output gets lrelu fused.
//   ne_e = mw * lrelu((asrc[src] + adst[n]) * (pd * ew))
//   out[n][:] = lrelu( (sum_e exp(ne-m) * z[src][:]) / max(sum exp, eps) )
// Edges come pre-sorted by dst (src_s/pd_s from scatter_k): coalesced reads.
// Lane owns dims {2*lane, 2*lane+1} (float2 gather: one dwordx2 per edge).
// ---------------------------------------------------------------------------
__global__ __launch_bounds__(256)
void gat_aggregate(const float* __restrict__ z, int ldz, int zHS,
                   const float* __restrict__ asrc, const float* __restrict__ adst, int aHS,
                   const float* __restrict__ pd_s,
                   const float* __restrict__ ewp, const float* __restrict__ mwp, int sHS,
                   const int* __restrict__ src_s, const int* __restrict__ csr_ptr,
                   float* __restrict__ outp, int ldo, int oHS, int N) {
  const int hd = blockIdx.y;
  z += (size_t)hd * zHS;
  asrc += (size_t)hd * aHS;
  adst += (size_t)hd * aHS;
  outp += (size_t)hd * oHS;
  const int wid = (int)((blockIdx.x * (unsigned)blockDim.x + threadIdx.x) >> 6);
  const int lane = threadIdx.x & 63;
  if (wid >= N) return;
  const int rs = csr_ptr[wid], re = csr_ptr[wid + 1];
  const int deg = re - rs;
  float* op = outp + (size_t)wid * ldo + (lane << 1);
  if (deg == 0) {  // empty mailbox -> zeros (matches reference)
    *(float2*)op = make_float2(0.f, 0.f);
    return;
  }
  const float ew = ewp[hd * sHS];
  const float mw = mwp[hd * sHS];
  const float adn = adst[wid];

  // ---- pass A: per-edge scores (lane-parallel), wave max ----
  float ne0 = -INFINITY, ne1 = -INFINITY;
  int s0 = 0, s1 = 0;
  {
    int j = rs + lane;
    if (j < re) {
      s0 = src_s[j];
      ne0 = mw * lrelu_f((asrc[s0] + adn) * (pd_s[j] * ew));
    }
    j += 64;
    if (j < re) {
      s1 = src_s[j];
      ne1 = mw * lrelu_f((asrc[s1] + adn) * (pd_s[j] * ew));
    }
  }
  float m = fmaxf(ne0, ne1);
  for (int j = rs + 128 + lane; j < re; j += 64) {  // statistically never (deg~Poisson(16))
    const int s = src_s[j];
    m = fmaxf(m, mw * lrelu_f((asrc[s] + adn) * (pd_s[j] * ew)));
  }
#pragma unroll
  for (int off = 32; off; off >>= 1) m = fmaxf(m, __shfl_xor(m, off));

  // ---- pass B: exp, sum, weighted gather-accumulate (x4 unroll for MLP) ----
  float accx = 0.f, accy = 0.f, ssum = 0.f;
  const int dd = lane << 1;
  for (int jj = 0; jj < deg; jj += 4) {
    float exk[4];
    int sk[4];
#pragma unroll
    for (int k = 0; k < 4; ++k) {
      const int q = jj + k;
      float ne;
      int s;
      if (q >= deg) {
        ne = -INFINITY; s = 0;               // exp -> 0, contributes nothing
      } else if (q < 64) {
        ne = __shfl(ne0, q); s = __shfl(s0, q);
      } else if (q < 128) {
        ne = __shfl(ne1, q - 64); s = __shfl(s1, q - 64);
      } else {                               // rare tail: broadcast recompute
        const int j = rs + q;
        s = src_s[j];
        ne = mw * lrelu_f((asrc[s] + adn) * (pd_s[j] * ew));
      }
      exk[k] = expf(ne - m);
      sk[k] = s;
    }
    float2 zv[4];
#pragma unroll
    for (int k = 0; k < 4; ++k)
      zv[k] = *(const float2*)(z + (size_t)sk[k] * ldz + dd);
#pragma unroll
    for (int k = 0; k < 4; ++k) {
      ssum += exk[k];
      accx = fmaf(exk[k], zv[k].x, accx);
      accy = fmaf(exk[k], zv[k].y, accy);
    }
  }
  const float denom = (ssum > 0.f) ? ssum : 1.f;
  *(float2*)op = make_float2(lrelu_f(accx / denom), lrelu_f(accy / denom));
}

// ---------------------------------------------------------------------------
// GRU gates + final lrelu. gi/gh: [N][384] (r,z,n slices), h: [N][128].
// ---------------------------------------------------------------------------
__global__ __launch_bounds__(256)
void gru_gate_k(const float* __restrict__ gi, const float* __restrict__ gh,
                const float* __restrict__ h, float* __restrict__ out, int total) {
  const int i = blockIdx.x * 256 + threadIdx.x;
  if (i >= total) return;
  const int n = i >> 7, d = i & 127;
  const float* gin = gi + (size_t)n * 384;
  const float* ghn = gh + (size_t)n * 384;
  const float r = 1.f / (1.f + expf(-(gin[d] + ghn[d])));
  const float zg = 1.f / (1.f + expf(-(gin[128 + d] + ghn[128 + d])));
  const float ng = tanhf(gin[256 + d] + r * ghn[256 + d]);
  const float v = (1.f - zg) * ng + zg * h[i];
  out[i] = lrelu_f(v);
}

// ---------------------------------------------------------------------------
extern "C" void kernel_launch(void* const* d_in, const int* in_sizes, int n_in,
                              void* d_out, int out_size, void* d_ws, size_t ws_size,
                              hipStream_t stream) {
  const int N = in_sizes[0] / 128;  // 40000 nodes
  const int E = in_sizes[1];        // 640000 edges

  const float* h     = (const float*)d_in[0];
  const float* pd    = (const float*)d_in[1];
  const int*   src   = (const int*)d_in[2];
  const int*   dst   = (const int*)d_in[3];
  const float* fcW   = (const float*)d_in[4];   // [4*128][128] = [512][128]
  const float* attnW = (const float*)d_in[5];   // [4][256]
  const float* edgew = (const float*)d_in[6];   // [4]
  const float* mw    = (const float*)d_in[7];   // [4]
  const float* ofcW  = (const float*)d_in[8];   // [128][512]
  const float* oattn = (const float*)d_in[9];   // [256]
  const float* oew   = (const float*)d_in[10];  // [1]
  const float* omw   = (const float*)d_in[11];  // [1]
  const float* Wih   = (const float*)d_in[12];  // [384][128]
  const float* Whh   = (const float*)d_in[13];  // [384][128]
  const float* bih   = (const float*)d_in[14];  // [384]
  const float* bhh   = (const float*)d_in[15];  // [384]
  float* out = (float*)d_out;

  // ---- workspace layout (all offsets 256B aligned) ----
  char* w = (char*)d_ws;
  size_t off = 0;
  auto alloc = [&](size_t bytes) -> char* {
    char* p = w + off;
    off += (bytes + 255) & ~(size_t)255;
    return p;
  };
  float* z     = (float*)alloc((size_t)N * 512 * 4);  // head FC out; later reused as gi [N][384]
  float* x     = (float*)alloc((size_t)N * 512 * 4);  // lrelu(concat heads); later reused as gh
  float* z2    = (float*)alloc((size_t)N * 128 * 4);  // out-layer FC
  float* asrc  = (float*)alloc((size_t)4 * N * 4);
  float* adst  = (float*)alloc((size_t)4 * N * 4);
  float* a2s   = (float*)alloc((size_t)N * 4);
  float* a2d   = (float*)alloc((size_t)N * 4);
  int* deg     = (int*)alloc((size_t)N * 4);
  int* ptr     = (int*)alloc((size_t)(N + 1) * 4);
  int* cursor  = (int*)alloc((size_t)N * 4);
  int* src_s   = (int*)alloc((size_t)E * 4);          // dst-sorted src
  float* pd_s  = (float*)alloc((size_t)E * 4);        // dst-sorted pd
  float* gi = z;     // [N][384] fits in z's [N][512]
  float* gh = x;     // ditto
  float* x2 = out;   // out-layer result lives in d_out until the GRU overwrites it
  (void)ws_size; (void)n_in; (void)out_size;

  const int nodeBlocks = (N + 3) / 4;   // one wave per node, 4 waves/block
  const int eBlocks = (E + 255) / 256;
  const int mBlocks = (N + 127) / 128;  // GEMM row-blocks (313)

  // 1) z = lrelu(h @ fcW^T)  (all 4 heads at once): M=N, Nn=512, K=128
  gemm_nt<128, true, false><<<dim3(512 / 128, mBlocks), 256, 0, stream>>>(h, fcW, nullptr, z, N, 512, 128);

  // 2) per-head attention scalars
  attn_heads_k<<<nodeBlocks, 256, 0, stream>>>(z, attnW, asrc, adst, N);

  // 3) CSR over dst (with dst-sorted src/pd copies)
  hipMemsetAsync(deg, 0, (size_t)N * 4, stream);
  hipMemsetAsync(cursor, 0, (size_t)N * 4, stream);
  hist_k<<<eBlocks, 256, 0, stream>>>(dst, deg, E);
  scan_k<<<1, 1024, 0, stream>>>(deg, ptr, N);
  scatter_k<<<eBlocks, 256, 0, stream>>>(dst, src, pd, ptr, cursor, src_s, pd_s, E);

  // 4) per-head segment softmax + aggregation -> x = lrelu(concat(heads))
  gat_aggregate<<<dim3(nodeBlocks, 4), 256, 0, stream>>>(
      z, 512, 128, asrc, adst, N, pd_s, edgew, mw, 1, src_s, ptr, x, 512, 128, N);

  // 5) z2 = lrelu(x @ ofcW^T): M=N, Nn=128, K=512  (64-wide tile: 626 blocks)
  gemm_nt<64, true, false><<<dim3(128 / 64, mBlocks), 256, 0, stream>>>(x, ofcW, nullptr, z2, N, 128, 512);

  // 6) out-layer attention scalars
  attn_out_k<<<nodeBlocks, 256, 0, stream>>>(z2, oattn, a2s, a2d, N);

  // 7) out-layer aggregation -> x2 = lrelu(gat_out)   (stored in d_out)
  gat_aggregate<<<dim3(nodeBlocks, 1), 256, 0, stream>>>(
      z2, 128, 0, a2s, a2d, 0, pd_s, oew, omw, 0, src_s, ptr, x2, 128, 0, N);

  // 8) GRU: gi = x2 @ Wih^T + bih ; gh = h @ Whh^T + bhh  (64-wide: 1878 blocks)
  gemm_nt<64, false, true><<<dim3(384 / 64, mBlocks), 256, 0, stream>>>(x2, Wih, bih, gi, N, 384, 128);
  gemm_nt<64, false, true><<<dim3(384 / 64, mBlocks), 256, 0, stream>>>(h, Whh, bhh, gh, N, 384, 128);

  // 9) gates + final lrelu -> d_out
  gru_gate_k<<<(N * 128 + 255) / 256, 256, 0, stream>>>(gi, gh, h, out, N * 128);
}

// Round 6
// 721.667 us; speedup vs baseline: 1.0122x; 1.0122x over previous
//
#include <hip/hip_runtime.h>
#include <math.h>

#define NEG_SLOPE 0.01f

__device__ __forceinline__ float lrelu_f(float x) { return x >= 0.f ? x : NEG_SLOPE * x; }

// ---------------------------------------------------------------------------
// GEMM: C[m][n] = act( sum_k A[m][k] * B[n][k] (+ bias[n]) )
// A: [M][K] row-major, B: [N][K] row-major (C = A @ B^T), all fp32.
// Tile: 128 rows x TN cols (TN in {64,128}), K-chunk 64, 256 threads,
// 8 x (TN/16) acc per thread. Requires N%TN==0, K%64==0. M arbitrary
// (A loads clamp to M-1, C stores predicated).
//
// TN=128: LDS 66KB -> 2 blocks/CU. TN=64: LDS 51KB -> 3 blocks/CU; used for
// narrow N (128, 384) where a 128-wide tile under-subscribes the grid
// (313 blocks on 256 CUs = 1 wave/SIMD = exposed LDS latency + barriers).
//
// LDS layout: transposed [k][m], row stride TN+4 words, 4-word-granular XOR
// column swizzle: word' = word ^ ((k>>2 & 15) << 2). Un-swizzled, staging
// writes are 8-way bank-conflicted (~2.94x, m136); swizzled they spread to
// 2 lanes/bank (free). Reads use the same key per kk: A-reads stay 16-lane
// broadcasts (free); B-reads: TN=128 4-way (1.58x), TN=64 2-way (free).
// All float4 LDS addresses stay 16B-aligned (keys live in word bits 2-5).
// ---------------------------------------------------------------------------
template<int TN, bool LRELU, bool BIAS>
__global__ __launch_bounds__(256)
void gemm_nt(const float* __restrict__ A, const float* __restrict__ B,
             const float* __restrict__ bias, float* __restrict__ C,
             int M, int Nn, int K) {
  constexpr int SB = TN + 4;       // Bs row stride (words)
  constexpr int CN = TN / 16;      // cols per thread (4 or 8)
  __shared__ float As[64 * 132];   // [k][m'] transposed + swizzled
  __shared__ float Bs[64 * SB];    // [k][n']
  const int tid = threadIdx.x;
  const int tx = tid & 15, ty = tid >> 4;
  const int bm = blockIdx.y << 7, bn = blockIdx.x * TN;
  const int tcol = tx << 2;        // k-offset 0..60
  const int trow = ty;             // 0..15
  const int wkey = tx << 2;        // write swizzle key ((k>>2)&15)<<2, k=tcol+c
  float acc[8][CN];
#pragma unroll
  for (int i = 0; i < 8; ++i)
#pragma unroll
    for (int j = 0; j < CN; ++j) acc[i][j] = 0.f;

  for (int k0 = 0; k0 < K; k0 += 64) {
#pragma unroll
    for (int i = 0; i < 8; ++i) {                 // stage A (128 rows)
      const int r = trow + (i << 4);
      int ar = bm + r; ar = ar < M ? ar : M - 1;  // clamp (predicated at store)
      const float4 va = *(const float4*)(A + (size_t)ar * K + k0 + tcol);
      const int rw = r ^ wkey;
      As[(tcol + 0) * 132 + rw] = va.x; As[(tcol + 1) * 132 + rw] = va.y;
      As[(tcol + 2) * 132 + rw] = va.z; As[(tcol + 3) * 132 + rw] = va.w;
    }
#pragma unroll
    for (int i = 0; i < TN / 16; ++i) {           // stage B (TN rows)
      const int r = trow + (i << 4);
      const float4 vb = *(const float4*)(B + (size_t)(bn + r) * K + k0 + tcol);
      const int rw = r ^ wkey;
      Bs[(tcol + 0) * SB + rw] = vb.x; Bs[(tcol + 1) * SB + rw] = vb.y;
      Bs[(tcol + 2) * SB + rw] = vb.z; Bs[(tcol + 3) * SB + rw] = vb.w;
    }
    __syncthreads();
    for (int kk4 = 0; kk4 < 64; kk4 += 4) {
      const int kxor = kk4;        // ((kk>>2)&15)<<2 == kk4 for kk in [kk4,kk4+4)
#pragma unroll
      for (int c = 0; c < 4; ++c) {
        const float* arow = As + (kk4 + c) * 132;
        const float* brow = Bs + (kk4 + c) * SB;
        const float4 a0 = *(const float4*)(arow + ((ty << 3) ^ kxor));
        const float4 a1 = *(const float4*)(arow + (((ty << 3) + 4) ^ kxor));
        const float av[8] = {a0.x, a0.y, a0.z, a0.w, a1.x, a1.y, a1.z, a1.w};
        float bv[CN];
        {
          const float4 b0 = *(const float4*)(brow + ((tx * CN) ^ kxor));
          bv[0] = b0.x; bv[1] = b0.y; bv[2] = b0.z; bv[3] = b0.w;
          if (CN == 8) {
            const float4 b1 = *(const float4*)(brow + ((tx * CN + 4) ^ kxor));
            bv[4] = b1.x; bv[5] = b1.y; bv[6] = b1.z; bv[7] = b1.w;
          }
        }
#pragma unroll
        for (int i = 0; i < 8; ++i)
#pragma unroll
          for (int j = 0; j < CN; ++j) acc[i][j] = fmaf(av[i], bv[j], acc[i][j]);
      }
    }
    __syncthreads();
  }

#pragma unroll
  for (int i = 0; i < 8; ++i) {
    const int row = bm + (ty << 3) + i;
    if (row >= M) break;
    const int col = bn + tx * CN;
    float v[CN];
#pragma unroll
    for (int j = 0; j < CN; ++j) {
      v[j] = acc[i][j];
      if (BIAS) v[j] += bias[col + j];
      if (LRELU) v[j] = lrelu_f(v[j]);
    }
#pragma unroll
    for (int q = 0; q < CN; q += 4)
      *(float4*)(C + (size_t)row * Nn + col + q) = make_float4(v[q], v[q + 1], v[q + 2], v[q + 3]);
  }
}

// ---------------------------------------------------------------------------
// a_src/a_dst for the 4 heads. z: [N][512] (head h = cols h*128..h*128+127).
// One wave per node; lanes h*16..h*16+15 own head h (8 dims each).
// attnW: [4][256]. Outputs: asrc/adst [4][N].
// ---------------------------------------------------------------------------
__global__ __launch_bounds__(256)
void attn_heads_k(const float* __restrict__ z, const float* __restrict__ attnW,
                  float* __restrict__ asrc, float* __restrict__ adst, int N) {
  const int wid = (int)((blockIdx.x * (unsigned)blockDim.x + threadIdx.x) >> 6);
  const int lane = threadIdx.x & 63;
  if (wid >= N) return;
  const int h = lane >> 4;
  const int dd = (lane & 15) << 3;
  const float* zp = z + (size_t)wid * 512 + h * 128 + dd;
  const float* aw = attnW + h * 256 + dd;
  const float4 z0 = *(const float4*)zp;
  const float4 z1 = *(const float4*)(zp + 4);
  const float4 w0 = *(const float4*)aw;
  const float4 w1 = *(const float4*)(aw + 4);
  const float4 w2 = *(const float4*)(aw + 128);
  const float4 w3 = *(const float4*)(aw + 132);
  float ps = z0.x * w0.x + z0.y * w0.y + z0.z * w0.z + z0.w * w0.w
           + z1.x * w1.x + z1.y * w1.y + z1.z * w1.z + z1.w * w1.w;
  float pq = z0.x * w2.x + z0.y * w2.y + z0.z * w2.z + z0.w * w2.w
           + z1.x * w3.x + z1.y * w3.y + z1.z * w3.z + z1.w * w3.w;
#pragma unroll
  for (int off = 8; off; off >>= 1) {
    ps += __shfl_xor(ps, off);
    pq += __shfl_xor(pq, off);
  }
  if ((lane & 15) == 0) {
    asrc[(size_t)h * N + wid] = ps;
    adst[(size_t)h * N + wid] = pq;
  }
}

// a_src/a_dst for the output layer. z2: [N][128]. attnW: [256]. One wave/node.
__global__ __launch_bounds__(256)
void attn_out_k(const float* __restrict__ z2, const float* __restrict__ attnW,
                float* __restrict__ asrc, float* __restrict__ adst, int N) {
  const int wid = (int)((blockIdx.x * (unsigned)blockDim.x + threadIdx.x) >> 6);
  const int lane = threadIdx.x & 63;
  if (wid >= N) return;
  const float* zp = z2 + (size_t)wid * 128;
  const float za = zp[lane], zb = zp[lane + 64];
  float ps = za * attnW[lane] + zb * attnW[lane + 64];
  float pq = za * attnW[128 + lane] + zb * attnW[192 + lane];
#pragma unroll
  for (int off = 32; off; off >>= 1) {
    ps += __shfl_xor(ps, off);
    pq += __shfl_xor(pq, off);
  }
  if (lane == 0) {
    asrc[wid] = ps;
    adst[wid] = pq;
  }
}

// ---------------------------------------------------------------------------
// CSR build over dst. scatter_k writes dst-sorted copies of src and pd
// directly (no eidx indirection): aggregates then read edges coalesced.
// ---------------------------------------------------------------------------
__global__ void hist_k(const int* __restrict__ dst, int* __restrict__ deg, int E) {
  const int i = blockIdx.x * 256 + threadIdx.x;
  if (i < E) atomicAdd(&deg[dst[i]], 1);
}

// Single-block exclusive scan (1024 thr): ptr[0]=0, ptr[i+1]=sum(deg[0..i]).
// Wave-level shuffle scans + wave-sum scan; 4 barriers per 1024 elements.
__global__ __launch_bounds__(1024)
void scan_k(const int* __restrict__ deg, int* __restrict__ ptr, int n) {
  __shared__ int wsum[16];
  __shared__ int carry_s;
  const int tid = threadIdx.x;
  const int lane = tid & 63, wv = tid >> 6;
  if (tid == 0) carry_s = 0;
  __syncthreads();
  for (int base = 0; base < n; base += 1024) {
    const int i = base + tid;
    int s = (i < n) ? deg[i] : 0;
#pragma unroll
    for (int off = 1; off < 64; off <<= 1) {  // inclusive wave scan
      const int t = __shfl_up(s, off);
      if (lane >= off) s += t;
    }
    if (lane == 63) wsum[wv] = s;
    __syncthreads();
    if (wv == 0 && lane < 16) {               // scan the 16 wave sums
      int ws = wsum[lane];
#pragma unroll
      for (int off = 1; off < 16; off <<= 1) {
        const int t = __shfl_up(ws, off);
        if (lane >= off) ws += t;
      }
      wsum[lane] = ws;
    }
    __syncthreads();
    const int wprefix = (wv == 0) ? 0 : wsum[wv - 1];
    const int carry = carry_s;
    if (i < n) ptr[i + 1] = carry + wprefix + s;
    __syncthreads();                          // everyone done reading carry_s/wsum
    if (tid == 1023) carry_s = carry + wsum[15];
    __syncthreads();
  }
  if (tid == 0) ptr[0] = 0;
}

__global__ void scatter_k(const int* __restrict__ dst, const int* __restrict__ src,
                          const float* __restrict__ pd, const int* __restrict__ ptr,
                          int* __restrict__ cursor,
                          int* __restrict__ src_s, float* __restrict__ pd_s, int E) {
  const int i = blockIdx.x * 256 + threadIdx.x;
  if (i < E) {
    const int d = dst[i];
    const int p = ptr[d] + atomicAdd(&cursor[d], 1);
    src_s[p] = src[i];
    pd_s[p] = pd[i];
  }
}

// ---------------------------------------------------------------------------
// Segment softmax + weighted aggregation for one GAT layer.
// One wave per dst node (grid.y = head). Output gets lrelu fused.
//   ne_e = mw * lrelu((asrc[src] + adst[n]) * (pd * ew))
//   out[n][:] = lrelu( (sum_e exp(ne-m) * z[src][:]) / max(sum exp, eps) )
//
// Pass A (lane-parallel): scores for lane's 2 edges, wave max, ex=exp(ne-m)
// per lane (2 expf/wave, not 64x redundant), wave-reduced ssum; (ex,src)
// pairs parked in LDS (4KB/block, wave-private -> no barrier).
// Pass B (half-wave): lanes 0-31 even edges, 32-63 odd edges; per iteration
// each lane: 1 ds_read_b64 (ex,src) [2-addr broadcast = free] + 1 dwordx4
// z-gather (4 dims) + 4 FMA. 4 edges/iter -> 2 gathers in flight. Final
// cross-half __shfl_xor(acc,32); lanes 0-31 store float4.
// ---------------------------------------------------------------------------
__global__ __launch_bounds__(256)
void gat_aggregate(const float* __restrict__ z, int ldz, int zHS,
                   const float* __restrict__ asrc, const float* __restrict__ adst, int aHS,
                   const float* __restrict__ pd_s,
                   const float* __restrict__ ewp, const float* __restrict__ mwp, int sHS,
                   const int* __restrict__ src_s, const int* __restrict__ csr_ptr,
                   float* __restrict__ outp, int ldo, int oHS, int N) {
  __shared__ float pair[4][128][2];   // [wave][edge slot][(ex, src-as-float)]
  const int hd = blockIdx.y;
  z += (size_t)hd * zHS;
  asrc += (size_t)hd * aHS;
  adst += (size_t)hd * aHS;
  outp += (size_t)hd * oHS;
  const int wib = threadIdx.x >> 6;   // wave in block
  const int wid = blockIdx.x * 4 + wib;
  const int lane = threadIdx.x & 63;
  if (wid >= N) return;
  const int rs = csr_ptr[wid], re = csr_ptr[wid + 1];
  const int deg = re - rs;
  const int l32 = lane & 31;
  const int half = lane >> 5;
  float* op = outp + (size_t)wid * ldo;
  if (deg == 0) {  // empty mailbox -> zeros (matches reference)
    if (half == 0) *(float4*)(op + (l32 << 2)) = make_float4(0.f, 0.f, 0.f, 0.f);
    return;
  }
  const float ew = ewp[hd * sHS];
  const float mw = mwp[hd * sHS];
  const float adn = adst[wid];

  // ---- pass A: scores, wave max, lane-parallel exp, ssum, park in LDS ----
  float ne0 = -INFINITY, ne1 = -INFINITY;
  int s0 = 0, s1 = 0;
  {
    int j = rs + lane;
    if (j < re) {
      s0 = src_s[j];
      ne0 = mw * lrelu_f((asrc[s0] + adn) * (pd_s[j] * ew));
    }
    j += 64;
    if (j < re) {
      s1 = src_s[j];
      ne1 = mw * lrelu_f((asrc[s1] + adn) * (pd_s[j] * ew));
    }
  }
  float m = fmaxf(ne0, ne1);
  for (int j = rs + 128 + lane; j < re; j += 64) {  // statistically never (deg~Poisson(16))
    const int s = src_s[j];
    m = fmaxf(m, mw * lrelu_f((asrc[s] + adn) * (pd_s[j] * ew)));
  }
#pragma unroll
  for (int off = 32; off; off >>= 1) m = fmaxf(m, __shfl_xor(m, off));

  const float ex0 = expf(ne0 - m);   // ne=-INF -> 0
  const float ex1 = expf(ne1 - m);
  float ss = ex0 + ex1;
  for (int j = rs + 128 + lane; j < re; j += 64) {  // rare tail: include in ssum
    const int s = src_s[j];
    ss += expf(mw * lrelu_f((asrc[s] + adn) * (pd_s[j] * ew)) - m);
  }
#pragma unroll
  for (int off = 32; off; off >>= 1) ss += __shfl_xor(ss, off);

  pair[wib][lane][0] = ex0;
  pair[wib][lane][1] = __int_as_float(s0);
  pair[wib][lane + 64][0] = ex1;
  pair[wib][lane + 64][1] = __int_as_float(s1);
  // wave-private LDS region: compiler-inserted lgkmcnt waits order the reads.

  // ---- pass B: half-wave gather-accumulate, 4 edges per iteration ----
  float a0 = 0.f, a1 = 0.f, a2 = 0.f, a3 = 0.f;
  const int zoff = l32 << 2;
  for (int q0 = 0; q0 < deg; q0 += 4) {
#pragma unroll
    for (int u = 0; u < 2; ++u) {
      const int q = q0 + (u << 1) + half;
      float exv; int sv;
      if (q < deg) {
        if (q < 128) {
          const float2 p = *(const float2*)&pair[wib][q][0];
          exv = p.x; sv = __float_as_int(p.y);
        } else {                    // rare tail: recompute (uniform per half)
          sv = src_s[rs + q];
          exv = expf(mw * lrelu_f((asrc[sv] + adn) * (pd_s[rs + q] * ew)) - m);
        }
      } else {
        exv = 0.f; sv = 0;          // contributes nothing
      }
      const float4 zv = *(const float4*)(z + (size_t)sv * ldz + zoff);
      a0 = fmaf(exv, zv.x, a0);
      a1 = fmaf(exv, zv.y, a1);
      a2 = fmaf(exv, zv.z, a2);
      a3 = fmaf(exv, zv.w, a3);
    }
  }
  a0 += __shfl_xor(a0, 32);
  a1 += __shfl_xor(a1, 32);
  a2 += __shfl_xor(a2, 32);
  a3 += __shfl_xor(a3, 32);
  if (half == 0) {
    const float rd = 1.f / ((ss > 0.f) ? ss : 1.f);
    *(float4*)(op + zoff) = make_float4(lrelu_f(a0 * rd), lrelu_f(a1 * rd),
                                        lrelu_f(a2 * rd), lrelu_f(a3 * rd));
  }
}

// ---------------------------------------------------------------------------
// GRU gates + final lrelu. gi/gh: [N][384] (r,z,n slices), h: [N][128].
// ---------------------------------------------------------------------------
__global__ __launch_bounds__(256)
void gru_gate_k(const float* __restrict__ gi, const float* __restrict__ gh,
                const float* __restrict__ h, float* __restrict__ out, int total) {
  const int i = blockIdx.x * 256 + threadIdx.x;
  if (i >= total) return;
  const int n = i >> 7, d = i & 127;
  const float* gin = gi + (size_t)n * 384;
  const float* ghn = gh + (size_t)n * 384;
  const float r = 1.f / (1.f + expf(-(gin[d] + ghn[d])));
  const float zg = 1.f / (1.f + expf(-(gin[128 + d] + ghn[128 + d])));
  const float ng = tanhf(gin[256 + d] + r * ghn[256 + d]);
  const float v = (1.f - zg) * ng + zg * h[i];
  out[i] = lrelu_f(v);
}

// ---------------------------------------------------------------------------
extern "C" void kernel_launch(void* const* d_in, const int* in_sizes, int n_in,
                              void* d_out, int out_size, void* d_ws, size_t ws_size,
                              hipStream_t stream) {
  const int N = in_sizes[0] / 128;  // 40000 nodes
  const int E = in_sizes[1];        // 640000 edges

  const float* h     = (const float*)d_in[0];
  const float* pd    = (const float*)d_in[1];
  const int*   src   = (const int*)d_in[2];
  const int*   dst   = (const int*)d_in[3];
  const float* fcW   = (const float*)d_in[4];   // [4*128][128] = [512][128]
  const float* attnW = (const float*)d_in[5];   // [4][256]
  const float* edgew = (const float*)d_in[6];   // [4]
  const float* mw    = (const float*)d_in[7];   // [4]
  const float* ofcW  = (const float*)d_in[8];   // [128][512]
  const float* oattn = (const float*)d_in[9];   // [256]
  const float* oew   = (const float*)d_in[10];  // [1]
  const float* omw   = (const float*)d_in[11];  // [1]
  const float* Wih   = (const float*)d_in[12];  // [384][128]
  const float* Whh   = (const float*)d_in[13];  // [384][128]
  const float* bih   = (const float*)d_in[14];  // [384]
  const float* bhh   = (const float*)d_in[15];  // [384]
  float* out = (float*)d_out;

  // ---- workspace layout (all offsets 256B aligned) ----
  char* w = (char*)d_ws;
  size_t off = 0;
  auto alloc = [&](size_t bytes) -> char* {
    char* p = w + off;
    off += (bytes + 255) & ~(size_t)255;
    return p;
  };
  float* z     = (float*)alloc((size_t)N * 512 * 4);  // head FC out; later reused as gi [N][384]
  float* x     = (float*)alloc((size_t)N * 512 * 4);  // lrelu(concat heads); later reused as gh
  float* z2    = (float*)alloc((size_t)N * 128 * 4);  // out-layer FC
  float* asrc  = (float*)alloc((size_t)4 * N * 4);
  float* adst  = (float*)alloc((size_t)4 * N * 4);
  float* a2s   = (float*)alloc((size_t)N * 4);
  float* a2d   = (float*)alloc((size_t)N * 4);
  int* deg     = (int*)alloc((size_t)N * 4);
  int* ptr     = (int*)alloc((size_t)(N + 1) * 4);
  int* cursor  = (int*)alloc((size_t)N * 4);
  int* src_s   = (int*)alloc((size_t)E * 4);          // dst-sorted src
  float* pd_s  = (float*)alloc((size_t)E * 4);        // dst-sorted pd
  float* gi = z;     // [N][384] fits in z's [N][512]
  float* gh = x;     // ditto
  float* x2 = out;   // out-layer result lives in d_out until the GRU overwrites it
  (void)ws_size; (void)n_in; (void)out_size;

  const int nodeBlocks = (N + 3) / 4;   // one wave per node, 4 waves/block
  const int eBlocks = (E + 255) / 256;
  const int mBlocks = (N + 127) / 128;  // GEMM row-blocks (313)

  // 1) z = lrelu(h @ fcW^T)  (all 4 heads at once): M=N, Nn=512, K=128
  gemm_nt<128, true, false><<<dim3(512 / 128, mBlocks), 256, 0, stream>>>(h, fcW, nullptr, z, N, 512, 128);

  // 2) per-head attention scalars
  attn_heads_k<<<nodeBlocks, 256, 0, stream>>>(z, attnW, asrc, adst, N);

  // 3) CSR over dst (with dst-sorted src/pd copies)
  hipMemsetAsync(deg, 0, (size_t)N * 4, stream);
  hipMemsetAsync(cursor, 0, (size_t)N * 4, stream);
  hist_k<<<eBlocks, 256, 0, stream>>>(dst, deg, E);
  scan_k<<<1, 1024, 0, stream>>>(deg, ptr, N);
  scatter_k<<<eBlocks, 256, 0, stream>>>(dst, src, pd, ptr, cursor, src_s, pd_s, E);

  // 4) per-head segment softmax + aggregation -> x = lrelu(concat(heads))
  gat_aggregate<<<dim3(nodeBlocks, 4), 256, 0, stream>>>(
      z, 512, 128, asrc, adst, N, pd_s, edgew, mw, 1, src_s, ptr, x, 512, 128, N);

  // 5) z2 = lrelu(x @ ofcW^T): M=N, Nn=128, K=512  (64-wide tile: 626 blocks)
  gemm_nt<64, true, false><<<dim3(128 / 64, mBlocks), 256, 0, stream>>>(x, ofcW, nullptr, z2, N, 128, 512);

  // 6) out-layer attention scalars
  attn_out_k<<<nodeBlocks, 256, 0, stream>>>(z2, oattn, a2s, a2d, N);

  // 7) out-layer aggregation -> x2 = lrelu(gat_out)   (stored in d_out)
  gat_aggregate<<<dim3(nodeBlocks, 1), 256, 0, stream>>>(
      z2, 128, 0, a2s, a2d, 0, pd_s, oew, omw, 0, src_s, ptr, x2, 128, 0, N);

  // 8) GRU: gi = x2 @ Wih^T + bih ; gh = h @ Whh^T + bhh  (64-wide: 1878 blocks)
  gemm_nt<64, false, true><<<dim3(384 / 64, mBlocks), 256, 0, stream>>>(x2, Wih, bih, gi, N, 384, 128);
  gemm_nt<64, false, true><<<dim3(384 / 64, mBlocks), 256, 0, stream>>>(h, Whh, bhh, gh, N, 384, 128);

  // 9) gates + final lrelu -> d_out
  gru_gate_k<<<(N * 128 + 255) / 256, 256, 0, stream>>>(gi, gh, h, out, N * 128);
}

// Round 7
// 658.238 us; speedup vs baseline: 1.1098x; 1.0964x over previous
//
#include <hip/hip_runtime.h>
#include <math.h>

#define NEG_SLOPE 0.01f

__device__ __forceinline__ float lrelu_f(float x) { return x >= 0.f ? x : NEG_SLOPE * x; }

typedef __attribute__((ext_vector_type(8))) short short8v;
typedef __attribute__((ext_vector_type(4))) short short4v;
typedef __attribute__((ext_vector_type(4))) float f32x4;

__device__ __forceinline__ unsigned short f2bf(float f) {  // fp32 -> bf16 RNE
  unsigned u = __float_as_uint(f);
  u += 0x7FFF + ((u >> 16) & 1);
  return (unsigned short)(u >> 16);
}
__device__ __forceinline__ float bf2f(unsigned short s) {
  return __uint_as_float((unsigned)s << 16);
}

// ---------------------------------------------------------------------------
// GEMM via bf16x3 MFMA: C[m][n] = act( sum_k A[m][k]*B[n][k] (+bias[n]) )
// A:[M][K], B:[N][K] row-major fp32. Split a=a_hi+a_lo (bf16), accumulate
// C += Ahi*Bhi + Ahi*Blo + Alo*Bhi via v_mfma_f32_16x16x32_bf16 (rel err
// ~1.5e-5). Tile BM=128 x TN, K-chunk 64, 256 thr (4 waves).
// TN=128: waves 2x2 (64x64 each, MI=NI=4), LDS 64KB -> 2 blk/CU.
// TN=64:  waves 4x1 (32x64, MI=2, NI=4), LDS 48KB -> 3 blk/CU (narrow N).
//
// Fragment layout (v_mfma_f32_16x16x32_bf16):
//   A: row=lane&15, k = {4g..4g+3} u {16+4g..19+4g}, g=lane>>4 (8 bf16/lane)
//   B: col=lane&15, same k-set            C/D: col=lane&15, row=4*(l>>4)+reg
// LDS stores k PERMUTED so a fragment is 8 contiguous shorts:
//   s(k) = (k>>5)*32 + ((k>>2)&3)*8 + ((k>>4)&1)*4 + (k&3)   (k in [0,64))
// plus XOR swizzle idx = row*64 + (s ^ ((row&7)<<3)): frag reads spread
// 16 rows over 8 banks (2-way = free); staging writes 4-way (~1.58x).
// ---------------------------------------------------------------------------
template<int TN, bool LRELU, bool BIAS>
__global__ __launch_bounds__(256)
void gemm_bf16x3(const float* __restrict__ A, const float* __restrict__ B,
                 const float* __restrict__ bias, float* __restrict__ C,
                 int M, int Nn, int K) {
  constexpr int MI = (TN == 128) ? 4 : 2;   // 16-row frags per wave
  constexpr int NI = 4;                      // 16-col frags per wave
  __shared__ short AsH[128 * 64], AsL[128 * 64];
  __shared__ short BsH[TN * 64],  BsL[TN * 64];
  const int tid = threadIdx.x;
  const int lane = tid & 63, w = tid >> 6;
  const int tx = tid & 15, ty = tid >> 4;
  const int bm = blockIdx.y << 7, bn = blockIdx.x * TN;
  const int m0 = (TN == 128) ? (w >> 1) * 64 : w * 32;
  const int n0 = (TN == 128) ? (w & 1) * 64 : 0;
  // staging k-permutation base for this thread's 4 consecutive k (kl=4*tx):
  const int sbase = (tx >> 3) * 32 + (tx & 3) * 8 + ((tx >> 2) & 1) * 4;
  const int g = lane >> 4;
  const int key = (lane & 7) << 3;          // frag-read XOR key ((row&7)<<3)
  const int arow = lane & 15;

  f32x4 acc[MI][NI];
#pragma unroll
  for (int i = 0; i < MI; ++i)
#pragma unroll
    for (int j = 0; j < NI; ++j) acc[i][j] = (f32x4){0.f, 0.f, 0.f, 0.f};

  for (int k0 = 0; k0 < K; k0 += 64) {
#pragma unroll
    for (int i = 0; i < 8; ++i) {           // stage A: 128 rows x 64 k
      const int r = ty + (i << 4);
      int ar = bm + r; ar = ar < M ? ar : M - 1;
      const float4 va = *(const float4*)(A + (size_t)ar * K + k0 + (tx << 2));
      short4v h, l;
      h[0] = (short)f2bf(va.x); l[0] = (short)f2bf(va.x - bf2f(h[0]));
      h[1] = (short)f2bf(va.y); l[1] = (short)f2bf(va.y - bf2f(h[1]));
      h[2] = (short)f2bf(va.z); l[2] = (short)f2bf(va.z - bf2f(h[2]));
      h[3] = (short)f2bf(va.w); l[3] = (short)f2bf(va.w - bf2f(h[3]));
      const int idx = r * 64 + (sbase ^ ((r & 7) << 3));
      *(short4v*)&AsH[idx] = h;
      *(short4v*)&AsL[idx] = l;
    }
#pragma unroll
    for (int i = 0; i < TN / 16; ++i) {     // stage B: TN rows x 64 k
      const int r = ty + (i << 4);
      const float4 vb = *(const float4*)(B + (size_t)(bn + r) * K + k0 + (tx << 2));
      short4v h, l;
      h[0] = (short)f2bf(vb.x); l[0] = (short)f2bf(vb.x - bf2f(h[0]));
      h[1] = (short)f2bf(vb.y); l[1] = (short)f2bf(vb.y - bf2f(h[1]));
      h[2] = (short)f2bf(vb.z); l[2] = (short)f2bf(vb.z - bf2f(h[2]));
      h[3] = (short)f2bf(vb.w); l[3] = (short)f2bf(vb.w - bf2f(h[3]));
      const int idx = r * 64 + (sbase ^ ((r & 7) << 3));
      *(short4v*)&BsH[idx] = h;
      *(short4v*)&BsL[idx] = l;
    }
    __syncthreads();
#pragma unroll
    for (int kh = 0; kh < 2; ++kh) {        // two K=32 MFMA steps per chunk
      const int sb = kh * 32 + g * 8;
      short8v aH[MI], aL[MI], bH[NI], bL[NI];
#pragma unroll
      for (int mi = 0; mi < MI; ++mi) {
        const int base = (m0 + arow + mi * 16) * 64 + (sb ^ key);
        aH[mi] = *(const short8v*)&AsH[base];
        aL[mi] = *(const short8v*)&AsL[base];
      }
#pragma unroll
      for (int ni = 0; ni < NI; ++ni) {
        const int base = (n0 + arow + ni * 16) * 64 + (sb ^ key);
        bH[ni] = *(const short8v*)&BsH[base];
        bL[ni] = *(const short8v*)&BsL[base];
      }
#pragma unroll
      for (int mi = 0; mi < MI; ++mi)
#pragma unroll
        for (int ni = 0; ni < NI; ++ni) {
          acc[mi][ni] = __builtin_amdgcn_mfma_f32_16x16x32_bf16(aH[mi], bH[ni], acc[mi][ni], 0, 0, 0);
          acc[mi][ni] = __builtin_amdgcn_mfma_f32_16x16x32_bf16(aH[mi], bL[ni], acc[mi][ni], 0, 0, 0);
          acc[mi][ni] = __builtin_amdgcn_mfma_f32_16x16x32_bf16(aL[mi], bH[ni], acc[mi][ni], 0, 0, 0);
        }
    }
    __syncthreads();
  }

  // epilogue: C/D frag layout col=lane&15, row=4*(lane>>4)+reg
  const int rg = (lane >> 4) << 2;
#pragma unroll
  for (int ni = 0; ni < NI; ++ni) {
    const int col = bn + n0 + ni * 16 + (lane & 15);
    const float bc = BIAS ? bias[col] : 0.f;
#pragma unroll
    for (int mi = 0; mi < MI; ++mi) {
#pragma unroll
      for (int r4 = 0; r4 < 4; ++r4) {
        const int row = bm + m0 + mi * 16 + rg + r4;
        if (row < M) {
          float v = acc[mi][ni][r4] + bc;
          if (LRELU) v = lrelu_f(v);
          C[(size_t)row * Nn + col] = v;
        }
      }
    }
  }
}

// ---------------------------------------------------------------------------
// a_src/a_dst for the 4 heads. z: [N][512]. One wave per node.
// ---------------------------------------------------------------------------
__global__ __launch_bounds__(256)
void attn_heads_k(const float* __restrict__ z, const float* __restrict__ attnW,
                  float* __restrict__ asrc, float* __restrict__ adst, int N) {
  const int wid = (int)((blockIdx.x * (unsigned)blockDim.x + threadIdx.x) >> 6);
  const int lane = threadIdx.x & 63;
  if (wid >= N) return;
  const int h = lane >> 4;
  const int dd = (lane & 15) << 3;
  const float* zp = z + (size_t)wid * 512 + h * 128 + dd;
  const float* aw = attnW + h * 256 + dd;
  const float4 z0 = *(const float4*)zp;
  const float4 z1 = *(const float4*)(zp + 4);
  const float4 w0 = *(const float4*)aw;
  const float4 w1 = *(const float4*)(aw + 4);
  const float4 w2 = *(const float4*)(aw + 128);
  const float4 w3 = *(const float4*)(aw + 132);
  float ps = z0.x * w0.x + z0.y * w0.y + z0.z * w0.z + z0.w * w0.w
           + z1.x * w1.x + z1.y * w1.y + z1.z * w1.z + z1.w * w1.w;
  float pq = z0.x * w2.x + z0.y * w2.y + z0.z * w2.z + z0.w * w2.w
           + z1.x * w3.x + z1.y * w3.y + z1.z * w3.z + z1.w * w3.w;
#pragma unroll
  for (int off = 8; off; off >>= 1) {
    ps += __shfl_xor(ps, off);
    pq += __shfl_xor(pq, off);
  }
  if ((lane & 15) == 0) {
    asrc[(size_t)h * N + wid] = ps;
    adst[(size_t)h * N + wid] = pq;
  }
}

// a_src/a_dst for the output layer. z2: [N][128]. One wave/node.
__global__ __launch_bounds__(256)
void attn_out_k(const float* __restrict__ z2, const float* __restrict__ attnW,
                float* __restrict__ asrc, float* __restrict__ adst, int N) {
  const int wid = (int)((blockIdx.x * (unsigned)blockDim.x + threadIdx.x) >> 6);
  const int lane = threadIdx.x & 63;
  if (wid >= N) return;
  const float* zp = z2 + (size_t)wid * 128;
  const float za = zp[lane], zb = zp[lane + 64];
  float ps = za * attnW[lane] + zb * attnW[lane + 64];
  float pq = za * attnW[128 + lane] + zb * attnW[192 + lane];
#pragma unroll
  for (int off = 32; off; off >>= 1) {
    ps += __shfl_xor(ps, off);
    pq += __shfl_xor(pq, off);
  }
  if (lane == 0) {
    asrc[wid] = ps;
    adst[wid] = pq;
  }
}

// ---------------------------------------------------------------------------
// CSR build over dst (scatter materializes dst-sorted src/pd).
// ---------------------------------------------------------------------------
__global__ void hist_k(const int* __restrict__ dst, int* __restrict__ deg, int E) {
  const int i = blockIdx.x * 256 + threadIdx.x;
  if (i < E) atomicAdd(&deg[dst[i]], 1);
}

__global__ __launch_bounds__(1024)
void scan_k(const int* __restrict__ deg, int* __restrict__ ptr, int n) {
  __shared__ int wsum[16];
  __shared__ int carry_s;
  const int tid = threadIdx.x;
  const int lane = tid & 63, wv = tid >> 6;
  if (tid == 0) carry_s = 0;
  __syncthreads();
  for (int base = 0; base < n; base += 1024) {
    const int i = base + tid;
    int s = (i < n) ? deg[i] : 0;
#pragma unroll
    for (int off = 1; off < 64; off <<= 1) {
      const int t = __shfl_up(s, off);
      if (lane >= off) s += t;
    }
    if (lane == 63) wsum[wv] = s;
    __syncthreads();
    if (wv == 0 && lane < 16) {
      int ws = wsum[lane];
#pragma unroll
      for (int off = 1; off < 16; off <<= 1) {
        const int t = __shfl_up(ws, off);
        if (lane >= off) ws += t;
      }
      wsum[lane] = ws;
    }
    __syncthreads();
    const int wprefix = (wv == 0) ? 0 : wsum[wv - 1];
    const int carry = carry_s;
    if (i < n) ptr[i + 1] = carry + wprefix + s;
    __syncthreads();
    if (tid == 1023) carry_s = carry + wsum[15];
    __syncthreads();
  }
  if (tid == 0) ptr[0] = 0;
}

__global__ void scatter_k(const int* __restrict__ dst, const int* __restrict__ src,
                          const float* __restrict__ pd, const int* __restrict__ ptr,
                          int* __restrict__ cursor,
                          int* __restrict__ src_s, float* __restrict__ pd_s, int E) {
  const int i = blockIdx.x * 256 + threadIdx.x;
  if (i < E) {
    const int d = dst[i];
    const int p = ptr[d] + atomicAdd(&cursor[d], 1);
    src_s[p] = src[i];
    pd_s[p] = pd[i];
  }
}

// ---------------------------------------------------------------------------
// Segment softmax + weighted aggregation (latency-bound gather kernel).
// Pass A: lane-parallel scores/exp/ssum, (ex,src) parked in wave-private LDS.
// Pass B: half-wave float4 gathers, 8 edges/iter (4 loads in flight/lane).
// ---------------------------------------------------------------------------
__global__ __launch_bounds__(256)
void gat_aggregate(const float* __restrict__ z, int ldz, int zHS,
                   const float* __restrict__ asrc, const float* __restrict__ adst, int aHS,
                   const float* __restrict__ pd_s,
                   const float* __restrict__ ewp, const float* __restrict__ mwp, int sHS,
                   const int* __restrict__ src_s, const int* __restrict__ csr_ptr,
                   float* __restrict__ outp, int ldo, int oHS, int N) {
  __shared__ float pair[4][128][2];
  const int hd = blockIdx.y;
  z += (size_t)hd * zHS;
  asrc += (size_t)hd * aHS;
  adst += (size_t)hd * aHS;
  outp += (size_t)hd * oHS;
  const int wib = threadIdx.x >> 6;
  const int wid = blockIdx.x * 4 + wib;
  const int lane = threadIdx.x & 63;
  if (wid >= N) return;
  const int rs = csr_ptr[wid], re = csr_ptr[wid + 1];
  const int deg = re - rs;
  const int l32 = lane & 31;
  const int half = lane >> 5;
  float* op = outp + (size_t)wid * ldo;
  if (deg == 0) {
    if (half == 0) *(float4*)(op + (l32 << 2)) = make_float4(0.f, 0.f, 0.f, 0.f);
    return;
  }
  const float ew = ewp[hd * sHS];
  const float mw = mwp[hd * sHS];
  const float adn = adst[wid];

  float ne0 = -INFINITY, ne1 = -INFINITY;
  int s0 = 0, s1 = 0;
  {
    int j = rs + lane;
    if (j < re) {
      s0 = src_s[j];
      ne0 = mw * lrelu_f((asrc[s0] + adn) * (pd_s[j] * ew));
    }
    j += 64;
    if (j < re) {
      s1 = src_s[j];
      ne1 = mw * lrelu_f((asrc[s1] + adn) * (pd_s[j] * ew));
    }
  }
  float m = fmaxf(ne0, ne1);
  for (int j = rs + 128 + lane; j < re; j += 64) {
    const int s = src_s[j];
    m = fmaxf(m, mw * lrelu_f((asrc[s] + adn) * (pd_s[j] * ew)));
  }
#pragma unroll
  for (int off = 32; off; off >>= 1) m = fmaxf(m, __shfl_xor(m, off));

  const float ex0 = expf(ne0 - m);
  const float ex1 = expf(ne1 - m);
  float ss = ex0 + ex1;
  for (int j = rs + 128 + lane; j < re; j += 64) {
    const int s = src_s[j];
    ss += expf(mw * lrelu_f((asrc[s] + adn) * (pd_s[j] * ew)) - m);
  }
#pragma unroll
  for (int off = 32; off; off >>= 1) ss += __shfl_xor(ss, off);

  pair[wib][lane][0] = ex0;
  pair[wib][lane][1] = __int_as_float(s0);
  pair[wib][lane + 64][0] = ex1;
  pair[wib][lane + 64][1] = __int_as_float(s1);

  float a0 = 0.f, a1 = 0.f, a2 = 0.f, a3 = 0.f;
  const int zoff = l32 << 2;
  for (int q0 = 0; q0 < deg; q0 += 8) {
#pragma unroll
    for (int u = 0; u < 4; ++u) {
      const int q = q0 + (u << 1) + half;
      float exv; int sv;
      if (q < deg) {
        if (q < 128) {
          const float2 p = *(const float2*)&pair[wib][q][0];
          exv = p.x; sv = __float_as_int(p.y);
        } else {
          sv = src_s[rs + q];
          exv = expf(mw * lrelu_f((asrc[sv] + adn) * (pd_s[rs + q] * ew)) - m);
        }
      } else {
        exv = 0.f; sv = 0;
      }
      const float4 zv = *(const float4*)(z + (size_t)sv * ldz + zoff);
      a0 = fmaf(exv, zv.x, a0);
      a1 = fmaf(exv, zv.y, a1);
      a2 = fmaf(exv, zv.z, a2);
      a3 = fmaf(exv, zv.w, a3);
    }
  }
  a0 += __shfl_xor(a0, 32);
  a1 += __shfl_xor(a1, 32);
  a2 += __shfl_xor(a2, 32);
  a3 += __shfl_xor(a3, 32);
  if (half == 0) {
    const float rd = 1.f / ((ss > 0.f) ? ss : 1.f);
    *(float4*)(op + zoff) = make_float4(lrelu_f(a0 * rd), lrelu_f(a1 * rd),
                                        lrelu_f(a2 * rd), lrelu_f(a3 * rd));
  }
}

// ---------------------------------------------------------------------------
// GRU gates + final lrelu.
// ---------------------------------------------------------------------------
__global__ __launch_bounds__(256)
void gru_gate_k(const float* __restrict__ gi, const float* __restrict__ gh,
                const float* __restrict__ h, float* __restrict__ out, int total) {
  const int i = blockIdx.x * 256 + threadIdx.x;
  if (i >= total) return;
  const int n = i >> 7, d = i & 127;
  const float* gin = gi + (size_t)n * 384;
  const float* ghn = gh + (size_t)n * 384;
  const float r = 1.f / (1.f + expf(-(gin[d] + ghn[d])));
  const float zg = 1.f / (1.f + expf(-(gin[128 + d] + ghn[128 + d])));
  const float ng = tanhf(gin[256 + d] + r * ghn[256 + d]);
  const float v = (1.f - zg) * ng + zg * h[i];
  out[i] = lrelu_f(v);
}

// ---------------------------------------------------------------------------
extern "C" void kernel_launch(void* const* d_in, const int* in_sizes, int n_in,
                              void* d_out, int out_size, void* d_ws, size_t ws_size,
                              hipStream_t stream) {
  const int N = in_sizes[0] / 128;
  const int E = in_sizes[1];

  const float* h     = (const float*)d_in[0];
  const float* pd    = (const float*)d_in[1];
  const int*   src   = (const int*)d_in[2];
  const int*   dst   = (const int*)d_in[3];
  const float* fcW   = (const float*)d_in[4];
  const float* attnW = (const float*)d_in[5];
  const float* edgew = (const float*)d_in[6];
  const float* mw    = (const float*)d_in[7];
  const float* ofcW  = (const float*)d_in[8];
  const float* oattn = (const float*)d_in[9];
  const float* oew   = (const float*)d_in[10];
  const float* omw   = (const float*)d_in[11];
  const float* Wih   = (const float*)d_in[12];
  const float* Whh   = (const float*)d_in[13];
  const float* bih   = (const float*)d_in[14];
  const float* bhh   = (const float*)d_in[15];
  float* out = (float*)d_out;

  char* w = (char*)d_ws;
  size_t off = 0;
  auto alloc = [&](size_t bytes) -> char* {
    char* p = w + off;
    off += (bytes + 255) & ~(size_t)255;
    return p;
  };
  float* z     = (float*)alloc((size_t)N * 512 * 4);
  float* x     = (float*)alloc((size_t)N * 512 * 4);
  float* z2    = (float*)alloc((size_t)N * 128 * 4);
  float* asrc  = (float*)alloc((size_t)4 * N * 4);
  float* adst  = (float*)alloc((size_t)4 * N * 4);
  float* a2s   = (float*)alloc((size_t)N * 4);
  float* a2d   = (float*)alloc((size_t)N * 4);
  int* deg     = (int*)alloc((size_t)N * 4);
  int* ptr     = (int*)alloc((size_t)(N + 1) * 4);
  int* cursor  = (int*)alloc((size_t)N * 4);
  int* src_s   = (int*)alloc((size_t)E * 4);
  float* pd_s  = (float*)alloc((size_t)E * 4);
  float* gi = z;
  float* gh = x;
  float* x2 = out;
  (void)ws_size; (void)n_in; (void)out_size;

  const int nodeBlocks = (N + 3) / 4;
  const int eBlocks = (E + 255) / 256;
  const int mBlocks = (N + 127) / 128;

  // 1) z = lrelu(h @ fcW^T): M=N, Nn=512, K=128  (bf16x3 MFMA)
  gemm_bf16x3<128, true, false><<<dim3(512 / 128, mBlocks), 256, 0, stream>>>(h, fcW, nullptr, z, N, 512, 128);

  // 2) per-head attention scalars
  attn_heads_k<<<nodeBlocks, 256, 0, stream>>>(z, attnW, asrc, adst, N);

  // 3) CSR over dst
  hipMemsetAsync(deg, 0, (size_t)N * 4, stream);
  hipMemsetAsync(cursor, 0, (size_t)N * 4, stream);
  hist_k<<<eBlocks, 256, 0, stream>>>(dst, deg, E);
  scan_k<<<1, 1024, 0, stream>>>(deg, ptr, N);
  scatter_k<<<eBlocks, 256, 0, stream>>>(dst, src, pd, ptr, cursor, src_s, pd_s, E);

  // 4) per-head aggregation -> x
  gat_aggregate<<<dim3(nodeBlocks, 4), 256, 0, stream>>>(
      z, 512, 128, asrc, adst, N, pd_s, edgew, mw, 1, src_s, ptr, x, 512, 128, N);

  // 5) z2 = lrelu(x @ ofcW^T): M=N, Nn=128, K=512
  gemm_bf16x3<64, true, false><<<dim3(128 / 64, mBlocks), 256, 0, stream>>>(x, ofcW, nullptr, z2, N, 128, 512);

  // 6) out-layer attention scalars
  attn_out_k<<<nodeBlocks, 256, 0, stream>>>(z2, oattn, a2s, a2d, N);

  // 7) out-layer aggregation -> x2 (in d_out)
  gat_aggregate<<<dim3(nodeBlocks, 1), 256, 0, stream>>>(
      z2, 128, 0, a2s, a2d, 0, pd_s, oew, omw, 0, src_s, ptr, x2, 128, 0, N);

  // 8) GRU GEMMs
  gemm_bf16x3<64, false, true><<<dim3(384 / 64, mBlocks), 256, 0, stream>>>(x2, Wih, bih, gi, N, 384, 128);
  gemm_bf16x3<64, false, true><<<dim3(384 / 64, mBlocks), 256, 0, stream>>>(h, Whh, bhh, gh, N, 384, 128);

  // 9) gates + final lrelu -> d_out
  gru_gate_k<<<(N * 128 + 255) / 256, 256, 0, stream>>>(gi, gh, h, out, N * 128);
}

// Round 10
// 612.417 us; speedup vs baseline: 1.1928x; 1.0748x over previous
//
#include <hip/hip_runtime.h>
#include <math.h>

#define NEG_SLOPE 0.01f

__device__ __forceinline__ float lrelu_f(float x) { return x >= 0.f ? x : NEG_SLOPE * x; }

typedef __attribute__((ext_vector_type(8))) short short8v;
typedef __attribute__((ext_vector_type(4))) short short4v;
typedef __attribute__((ext_vector_type(4))) float f32x4;
typedef __attribute__((ext_vector_type(8))) _Float16 half8v;
typedef __attribute__((ext_vector_type(4))) _Float16 half4v;

__device__ __forceinline__ unsigned short f2bf(float f) {  // fp32 -> bf16 RNE
  unsigned u = __float_as_uint(f);
  u += 0x7FFF + ((u >> 16) & 1);
  return (unsigned short)(u >> 16);
}
__device__ __forceinline__ float bf2f(unsigned short s) {
  return __uint_as_float((unsigned)s << 16);
}

// ---------------------------------------------------------------------------
// Split fp32 -> planar bf16 (hi) + bf16 (lo residual). Grid-stride, float4.
// ---------------------------------------------------------------------------
__global__ __launch_bounds__(256)
void split_bf16_k(const float* __restrict__ in, short* __restrict__ H,
                  short* __restrict__ L, int n4) {
  const int stride = gridDim.x * 256;
  for (int i = blockIdx.x * 256 + threadIdx.x; i < n4; i += stride) {
    const float4 v = ((const float4*)in)[i];
    short4v h, l;
    h[0] = (short)f2bf(v.x); l[0] = (short)f2bf(v.x - bf2f(h[0]));
    h[1] = (short)f2bf(v.y); l[1] = (short)f2bf(v.y - bf2f(h[1]));
    h[2] = (short)f2bf(v.z); l[2] = (short)f2bf(v.z - bf2f(h[2]));
    h[3] = (short)f2bf(v.w); l[3] = (short)f2bf(v.w - bf2f(h[3]));
    ((short4v*)H)[i] = h;
    ((short4v*)L)[i] = l;
  }
}

// ---------------------------------------------------------------------------
// GEMM via bf16x3 MFMA on PRE-SPLIT planar bf16 inputs (see r7/r8 notes).
// Optionally also writes an fp16 copy of C (gather plane for aggregates).
// ---------------------------------------------------------------------------
template<int TN, bool LRELU, bool BIAS, bool HOUT>
__global__ __launch_bounds__(256)
void gemm_bf16x3(const short* __restrict__ AH, const short* __restrict__ AL,
                 const short* __restrict__ BH, const short* __restrict__ BL,
                 const float* __restrict__ bias, float* __restrict__ C,
                 _Float16* __restrict__ Ch, int M, int Nn, int K) {
  constexpr int MI = (TN == 128) ? 4 : 2;
  constexpr int NI = 4;
  __shared__ short AsH[128 * 64], AsL[128 * 64];
  __shared__ short BsH[TN * 64],  BsL[TN * 64];
  const int tid = threadIdx.x;
  const int lane = tid & 63, w = tid >> 6;
  const int tx = tid & 15, ty = tid >> 4;
  const int bm = blockIdx.y << 7, bn = blockIdx.x * TN;
  const int m0 = (TN == 128) ? (w >> 1) * 64 : w * 32;
  const int n0 = (TN == 128) ? (w & 1) * 64 : 0;
  const int sbase = (tx >> 3) * 32 + (tx & 3) * 8 + ((tx >> 2) & 1) * 4;
  const int g = lane >> 4;
  const int key = (lane & 7) << 3;
  const int arow = lane & 15;

  f32x4 acc[MI][NI];
#pragma unroll
  for (int i = 0; i < MI; ++i)
#pragma unroll
    for (int j = 0; j < NI; ++j) acc[i][j] = (f32x4){0.f, 0.f, 0.f, 0.f};

  for (int k0 = 0; k0 < K; k0 += 64) {
#pragma unroll
    for (int i = 0; i < 8; ++i) {           // stage A: 128 rows x 64 k
      const int r = ty + (i << 4);
      int ar = bm + r; ar = ar < M ? ar : M - 1;
      const size_t go = (size_t)ar * K + k0 + (tx << 2);
      const short4v h = *(const short4v*)(AH + go);
      const short4v l = *(const short4v*)(AL + go);
      const int idx = r * 64 + (sbase ^ ((r & 7) << 3));
      *(short4v*)&AsH[idx] = h;
      *(short4v*)&AsL[idx] = l;
    }
#pragma unroll
    for (int i = 0; i < TN / 16; ++i) {     // stage B: TN rows x 64 k
      const int r = ty + (i << 4);
      const size_t go = (size_t)(bn + r) * K + k0 + (tx << 2);
      const short4v h = *(const short4v*)(BH + go);
      const short4v l = *(const short4v*)(BL + go);
      const int idx = r * 64 + (sbase ^ ((r & 7) << 3));
      *(short4v*)&BsH[idx] = h;
      *(short4v*)&BsL[idx] = l;
    }
    __syncthreads();
#pragma unroll
    for (int kh = 0; kh < 2; ++kh) {        // two K=32 MFMA steps per chunk
      const int sb = kh * 32 + g * 8;
      short8v aH[MI], aL[MI], bH[NI], bL[NI];
#pragma unroll
      for (int mi = 0; mi < MI; ++mi) {
        const int base = (m0 + arow + mi * 16) * 64 + (sb ^ key);
        aH[mi] = *(const short8v*)&AsH[base];
        aL[mi] = *(const short8v*)&AsL[base];
      }
#pragma unroll
      for (int ni = 0; ni < NI; ++ni) {
        const int base = (n0 + arow + ni * 16) * 64 + (sb ^ key);
        bH[ni] = *(const short8v*)&BsH[base];
        bL[ni] = *(const short8v*)&BsL[base];
      }
#pragma unroll
      for (int mi = 0; mi < MI; ++mi)
#pragma unroll
        for (int ni = 0; ni < NI; ++ni) {
          acc[mi][ni] = __builtin_amdgcn_mfma_f32_16x16x32_bf16(aH[mi], bH[ni], acc[mi][ni], 0, 0, 0);
          acc[mi][ni] = __builtin_amdgcn_mfma_f32_16x16x32_bf16(aH[mi], bL[ni], acc[mi][ni], 0, 0, 0);
          acc[mi][ni] = __builtin_amdgcn_mfma_f32_16x16x32_bf16(aL[mi], bH[ni], acc[mi][ni], 0, 0, 0);
        }
    }
    __syncthreads();
  }

  const int rg = (lane >> 4) << 2;
#pragma unroll
  for (int ni = 0; ni < NI; ++ni) {
    const int col = bn + n0 + ni * 16 + (lane & 15);
    const float bc = BIAS ? bias[col] : 0.f;
#pragma unroll
    for (int mi = 0; mi < MI; ++mi) {
#pragma unroll
      for (int r4 = 0; r4 < 4; ++r4) {
        const int row = bm + m0 + mi * 16 + rg + r4;
        if (row < M) {
          float v = acc[mi][ni][r4] + bc;
          if (LRELU) v = lrelu_f(v);
          C[(size_t)row * Nn + col] = v;
          if (HOUT) Ch[(size_t)row * Nn + col] = (_Float16)v;
        }
      }
    }
  }
}

// ---------------------------------------------------------------------------
// a_src/a_dst for the 4 heads. z: [N][512]. One wave per node.
// ---------------------------------------------------------------------------
__global__ __launch_bounds__(256)
void attn_heads_k(const float* __restrict__ z, const float* __restrict__ attnW,
                  float* __restrict__ asrc, float* __restrict__ adst, int N) {
  const int wid = (int)((blockIdx.x * (unsigned)blockDim.x + threadIdx.x) >> 6);
  const int lane = threadIdx.x & 63;
  if (wid >= N) return;
  const int h = lane >> 4;
  const int dd = (lane & 15) << 3;
  const float* zp = z + (size_t)wid * 512 + h * 128 + dd;
  const float* aw = attnW + h * 256 + dd;
  const float4 z0 = *(const float4*)zp;
  const float4 z1 = *(const float4*)(zp + 4);
  const float4 w0 = *(const float4*)aw;
  const float4 w1 = *(const float4*)(aw + 4);
  const float4 w2 = *(const float4*)(aw + 128);
  const float4 w3 = *(const float4*)(aw + 132);
  float ps = z0.x * w0.x + z0.y * w0.y + z0.z * w0.z + z0.w * w0.w
           + z1.x * w1.x + z1.y * w1.y + z1.z * w1.z + z1.w * w1.w;
  float pq = z0.x * w2.x + z0.y * w2.y + z0.z * w2.z + z0.w * w2.w
           + z1.x * w3.x + z1.y * w3.y + z1.z * w3.z + z1.w * w3.w;
#pragma unroll
  for (int off = 8; off; off >>= 1) {
    ps += __shfl_xor(ps, off);
    pq += __shfl_xor(pq, off);
  }
  if ((lane & 15) == 0) {
    asrc[(size_t)h * N + wid] = ps;
    adst[(size_t)h * N + wid] = pq;
  }
}

// a_src/a_dst for the output layer. z2: [N][128]. One wave/node.
__global__ __launch_bounds__(256)
void attn_out_k(const float* __restrict__ z2, const float* __restrict__ attnW,
                float* __restrict__ asrc, float* __restrict__ adst, int N) {
  const int wid = (int)((blockIdx.x * (unsigned)blockDim.x + threadIdx.x) >> 6);
  const int lane = threadIdx.x & 63;
  if (wid >= N) return;
  const float* zp = z2 + (size_t)wid * 128;
  const float za = zp[lane], zb = zp[lane + 64];
  float ps = za * attnW[lane] + zb * attnW[lane + 64];
  float pq = za * attnW[128 + lane] + zb * attnW[192 + lane];
#pragma unroll
  for (int off = 32; off; off >>= 1) {
    ps += __shfl_xor(ps, off);
    pq += __shfl_xor(pq, off);
  }
  if (lane == 0) {
    asrc[wid] = ps;
    adst[wid] = pq;
  }
}

// ---------------------------------------------------------------------------
// CSR build over dst (scatter materializes dst-sorted src/pd).
// ---------------------------------------------------------------------------
__global__ void hist_k(const int* __restrict__ dst, int* __restrict__ deg, int E) {
  const int i = blockIdx.x * 256 + threadIdx.x;
  if (i < E) atomicAdd(&deg[dst[i]], 1);
}

__global__ __launch_bounds__(1024)
void scan_k(const int* __restrict__ deg, int* __restrict__ ptr, int n) {
  __shared__ int wsum[16];
  __shared__ int carry_s;
  const int tid = threadIdx.x;
  const int lane = tid & 63, wv = tid >> 6;
  if (tid == 0) carry_s = 0;
  __syncthreads();
  for (int base = 0; base < n; base += 1024) {
    const int i = base + tid;
    int s = (i < n) ? deg[i] : 0;
#pragma unroll
    for (int off = 1; off < 64; off <<= 1) {
      const int t = __shfl_up(s, off);
      if (lane >= off) s += t;
    }
    if (lane == 63) wsum[wv] = s;
    __syncthreads();
    if (wv == 0 && lane < 16) {
      int ws = wsum[lane];
#pragma unroll
      for (int off = 1; off < 16; off <<= 1) {
        const int t = __shfl_up(ws, off);
        if (lane >= off) ws += t;
      }
      wsum[lane] = ws;
    }
    __syncthreads();
    const int wprefix = (wv == 0) ? 0 : wsum[wv - 1];
    const int carry = carry_s;
    if (i < n) ptr[i + 1] = carry + wprefix + s;
    __syncthreads();
    if (tid == 1023) carry_s = carry + wsum[15];
    __syncthreads();
  }
  if (tid == 0) ptr[0] = 0;
}

__global__ void scatter_k(const int* __restrict__ dst, const int* __restrict__ src,
                          const float* __restrict__ pd, const int* __restrict__ ptr,
                          int* __restrict__ cursor,
                          int* __restrict__ src_s, float* __restrict__ pd_s, int E) {
  const int i = blockIdx.x * 256 + threadIdx.x;
  if (i < E) {
    const int d = dst[i];
    const int p = ptr[d] + atomicAdd(&cursor[d], 1);
    src_s[p] = src[i];
    pd_s[p] = pd[i];
  }
}

// ---------------------------------------------------------------------------
// FUSED 4-head segment softmax + aggregation. One wave per dst node.
// Pass A: per-lane 2 edges x 4 head scores; per-head wave max/sum; (ex[4],src)
// parked in wave-private LDS. Pass B: lane owns 8 cols of head (lane>>4);
// per edge ONE 16B fp16 gather (64 lanes cover the 2KB row once); no
// cross-lane reduce. Output x[n][512] with fused lrelu.
// ---------------------------------------------------------------------------
__global__ __launch_bounds__(256)
void gat_heads_fused(const _Float16* __restrict__ zh,
                     const float* __restrict__ asrc, const float* __restrict__ adst,
                     const float* __restrict__ pd_s,
                     const float* __restrict__ ewp, const float* __restrict__ mwp,
                     const int* __restrict__ src_s, const int* __restrict__ csr_ptr,
                     float* __restrict__ outp, int N) {
  __shared__ float pair[4][128][5];   // [wave][slot][(ex0..ex3, src)]
  const int wib = threadIdx.x >> 6;
  const int wid = blockIdx.x * 4 + wib;
  const int lane = threadIdx.x & 63;
  if (wid >= N) return;
  const int rs = csr_ptr[wid], re = csr_ptr[wid + 1];
  const int deg = re - rs;
  const int hh = lane >> 4;           // head owned in pass B
  const int c = lane << 3;            // 8 cols owned
  float* op = outp + (size_t)wid * 512 + c;
  if (deg == 0) {
    *(float4*)op = make_float4(0.f, 0.f, 0.f, 0.f);
    *(float4*)(op + 4) = make_float4(0.f, 0.f, 0.f, 0.f);
    return;
  }
  float ew[4], mwv[4], adn[4];
#pragma unroll
  for (int h = 0; h < 4; ++h) {
    ew[h] = ewp[h]; mwv[h] = mwp[h];
    adn[h] = adst[(size_t)h * N + wid];
  }
  const int j0 = rs + lane, j1 = j0 + 64;
  const bool v0 = j0 < re, v1 = j1 < re;
  const int s0 = v0 ? src_s[j0] : 0;
  const float p0 = v0 ? pd_s[j0] : 0.f;
  const int s1 = v1 ? src_s[j1] : 0;
  const float p1 = v1 ? pd_s[j1] : 0.f;
  float ne0[4], ne1[4], m[4];
#pragma unroll
  for (int h = 0; h < 4; ++h) {
    const float a0 = asrc[(size_t)h * N + s0];
    const float a1 = asrc[(size_t)h * N + s1];
    ne0[h] = v0 ? mwv[h] * lrelu_f((a0 + adn[h]) * (p0 * ew[h])) : -INFINITY;
    ne1[h] = v1 ? mwv[h] * lrelu_f((a1 + adn[h]) * (p1 * ew[h])) : -INFINITY;
    m[h] = fmaxf(ne0[h], ne1[h]);
  }
  for (int j = rs + 128 + lane; j < re; j += 64) {  // statistically never
    const int s = src_s[j];
    const float p = pd_s[j];
#pragma unroll
    for (int h = 0; h < 4; ++h)
      m[h] = fmaxf(m[h], mwv[h] * lrelu_f((asrc[(size_t)h * N + s] + adn[h]) * (p * ew[h])));
  }
#pragma unroll
  for (int h = 0; h < 4; ++h)
#pragma unroll
    for (int off = 32; off; off >>= 1) m[h] = fmaxf(m[h], __shfl_xor(m[h], off));

  float ss[4];
#pragma unroll
  for (int h = 0; h < 4; ++h) {
    const float e0 = expf(ne0[h] - m[h]);   // -INF -> 0
    const float e1 = expf(ne1[h] - m[h]);
    pair[wib][lane][h] = e0;
    pair[wib][lane + 64][h] = e1;
    ss[h] = e0 + e1;
  }
  pair[wib][lane][4] = __int_as_float(s0);
  pair[wib][lane + 64][4] = __int_as_float(s1);
  for (int j = rs + 128 + lane; j < re; j += 64) {  // tail into ss only
    const int s = src_s[j];
    const float p = pd_s[j];
#pragma unroll
    for (int h = 0; h < 4; ++h)
      ss[h] += expf(mwv[h] * lrelu_f((asrc[(size_t)h * N + s] + adn[h]) * (p * ew[h])) - m[h]);
  }
#pragma unroll
  for (int h = 0; h < 4; ++h)
#pragma unroll
    for (int off = 32; off; off >>= 1) ss[h] += __shfl_xor(ss[h], off);

  // ---- pass B: 1x16B fp16 gather per edge per lane, 2 edges in flight ----
  float a[8] = {0.f, 0.f, 0.f, 0.f, 0.f, 0.f, 0.f, 0.f};
  for (int q0 = 0; q0 < deg; q0 += 2) {
#pragma unroll
    for (int u = 0; u < 2; ++u) {
      const int q = q0 + u;
      float exv; int sv;
      if (q < deg) {
        if (q < 128) {
          exv = pair[wib][q][hh];
          sv = __float_as_int(pair[wib][q][4]);
        } else {                    // rare tail: recompute for own head
          sv = src_s[rs + q];
          exv = expf(mwv[hh] * lrelu_f((asrc[(size_t)hh * N + sv] + adn[hh]) * (pd_s[rs + q] * ew[hh])) - m[hh]);
        }
      } else {
        exv = 0.f; sv = 0;
      }
      const half8v zv = *(const half8v*)(zh + (size_t)sv * 512 + c);
#pragma unroll
      for (int t = 0; t < 8; ++t) a[t] = fmaf(exv, (float)zv[t], a[t]);
    }
  }
  const float rd = 1.f / ((ss[hh] > 0.f) ? ss[hh] : 1.f);
  *(float4*)op = make_float4(lrelu_f(a[0] * rd), lrelu_f(a[1] * rd),
                             lrelu_f(a[2] * rd), lrelu_f(a[3] * rd));
  *(float4*)(op + 4) = make_float4(lrelu_f(a[4] * rd), lrelu_f(a[5] * rd),
                                   lrelu_f(a[6] * rd), lrelu_f(a[7] * rd));
}

// ---------------------------------------------------------------------------
// Out-layer segment softmax + aggregation (single head, fp16 z2 gather).
// Same structure as the r6-validated kernel; half-wave, 8B half4 gathers.
// ---------------------------------------------------------------------------
__global__ __launch_bounds__(256)
void gat_out_aggregate(const _Float16* __restrict__ zh,
                       const float* __restrict__ asrc, const float* __restrict__ adst,
                       const float* __restrict__ pd_s,
                       const float* __restrict__ ewp, const float* __restrict__ mwp,
                       const int* __restrict__ src_s, const int* __restrict__ csr_ptr,
                       float* __restrict__ outp, int N) {
  __shared__ float pair[4][128][2];
  const int wib = threadIdx.x >> 6;
  const int wid = blockIdx.x * 4 + wib;
  const int lane = threadIdx.x & 63;
  if (wid >= N) return;
  const int rs = csr_ptr[wid], re = csr_ptr[wid + 1];
  const int deg = re - rs;
  const int l32 = lane & 31;
  const int half = lane >> 5;
  float* op = outp + (size_t)wid * 128;
  if (deg == 0) {
    if (half == 0) *(float4*)(op + (l32 << 2)) = make_float4(0.f, 0.f, 0.f, 0.f);
    return;
  }
  const float ew = ewp[0];
  const float mw = mwp[0];
  const float adn = adst[wid];

  float ne0 = -INFINITY, ne1 = -INFINITY;
  int s0 = 0, s1 = 0;
  {
    int j = rs + lane;
    if (j < re) {
      s0 = src_s[j];
      ne0 = mw * lrelu_f((asrc[s0] + adn) * (pd_s[j] * ew));
    }
    j += 64;
    if (j < re) {
      s1 = src_s[j];
      ne1 = mw * lrelu_f((asrc[s1] + adn) * (pd_s[j] * ew));
    }
  }
  float m = fmaxf(ne0, ne1);
  for (int j = rs + 128 + lane; j < re; j += 64) {
    const int s = src_s[j];
    m = fmaxf(m, mw * lrelu_f((asrc[s] + adn) * (pd_s[j] * ew)));
  }
#pragma unroll
  for (int off = 32; off; off >>= 1) m = fmaxf(m, __shfl_xor(m, off));

  const float ex0 = expf(ne0 - m);
  const float ex1 = expf(ne1 - m);
  float ss = ex0 + ex1;
  for (int j = rs + 128 + lane; j < re; j += 64) {
    const int s = src_s[j];
    ss += expf(mw * lrelu_f((asrc[s] + adn) * (pd_s[j] * ew)) - m);
  }
#pragma unroll
  for (int off = 32; off; off >>= 1) ss += __shfl_xor(ss, off);

  pair[wib][lane][0] = ex0;
  pair[wib][lane][1] = __int_as_float(s0);
  pair[wib][lane + 64][0] = ex1;
  pair[wib][lane + 64][1] = __int_as_float(s1);

  float a0 = 0.f, a1 = 0.f, a2 = 0.f, a3 = 0.f;
  const int zoff = l32 << 2;
  for (int q0 = 0; q0 < deg; q0 += 4) {
#pragma unroll
    for (int u = 0; u < 2; ++u) {
      const int q = q0 + (u << 1) + half;
      float exv; int sv;
      if (q < deg) {
        if (q < 128) {
          const float2 p = *(const float2*)&pair[wib][q][0];
          exv = p.x; sv = __float_as_int(p.y);
        } else {
          sv = src_s[rs + q];
          exv = expf(mw * lrelu_f((asrc[sv] + adn) * (pd_s[rs + q] * ew)) - m);
        }
      } else {
        exv = 0.f; sv = 0;
      }
      const half4v zv = *(const half4v*)(zh + (size_t)sv * 128 + zoff);
      a0 = fmaf(exv, (float)zv[0], a0);
      a1 = fmaf(exv, (float)zv[1], a1);
      a2 = fmaf(exv, (float)zv[2], a2);
      a3 = fmaf(exv, (float)zv[3], a3);
    }
  }
  a0 += __shfl_xor(a0, 32);
  a1 += __shfl_xor(a1, 32);
  a2 += __shfl_xor(a2, 32);
  a3 += __shfl_xor(a3, 32);
  if (half == 0) {
    const float rd = 1.f / ((ss > 0.f) ? ss : 1.f);
    *(float4*)(op + zoff) = make_float4(lrelu_f(a0 * rd), lrelu_f(a1 * rd),
                                        lrelu_f(a2 * rd), lrelu_f(a3 * rd));
  }
}

// ---------------------------------------------------------------------------
// GRU gates + final lrelu.
// ---------------------------------------------------------------------------
__global__ __launch_bounds__(256)
void gru_gate_k(const float* __restrict__ gi, const float* __restrict__ gh,
                const float* __restrict__ h, float* __restrict__ out, int total) {
  const int i = blockIdx.x * 256 + threadIdx.x;
  if (i >= total) return;
  const int n = i >> 7, d = i & 127;
  const float* gin = gi + (size_t)n * 384;
  const float* ghn = gh + (size_t)n * 384;
  const float r = 1.f / (1.f + expf(-(gin[d] + ghn[d])));
  const float zg = 1.f / (1.f + expf(-(gin[128 + d] + ghn[128 + d])));
  const float ng = tanhf(gin[256 + d] + r * ghn[256 + d]);
  const float v = (1.f - zg) * ng + zg * h[i];
  out[i] = lrelu_f(v);
}

// ---------------------------------------------------------------------------
extern "C" void kernel_launch(void* const* d_in, const int* in_sizes, int n_in,
                              void* d_out, int out_size, void* d_ws, size_t ws_size,
                              hipStream_t stream) {
  const int N = in_sizes[0] / 128;
  const int E = in_sizes[1];

  const float* h     = (const float*)d_in[0];
  const float* pd    = (const float*)d_in[1];
  const int*   src   = (const int*)d_in[2];
  const int*   dst   = (const int*)d_in[3];
  const float* fcW   = (const float*)d_in[4];
  const float* attnW = (const float*)d_in[5];
  const float* edgew = (const float*)d_in[6];
  const float* mw    = (const float*)d_in[7];
  const float* ofcW  = (const float*)d_in[8];
  const float* oattn = (const float*)d_in[9];
  const float* oew   = (const float*)d_in[10];
  const float* omw   = (const float*)d_in[11];
  const float* Wih   = (const float*)d_in[12];
  const float* Whh   = (const float*)d_in[13];
  const float* bih   = (const float*)d_in[14];
  const float* bhh   = (const float*)d_in[15];
  float* out = (float*)d_out;

  char* w = (char*)d_ws;
  size_t off = 0;
  auto alloc = [&](size_t bytes) -> char* {
    char* p = w + off;
    off += (bytes + 255) & ~(size_t)255;
    return p;
  };
  // Region A: z fp32 -> (after heads-agg) xH+xL -> (after GEMM2) gh
  char* regA = alloc((size_t)N * 512 * 4);
  float* z   = (float*)regA;
  short* xH  = (short*)regA;
  short* xL  = (short*)(regA + (size_t)N * 512 * 2);
  float* gh  = (float*)regA;
  // Region B: x fp32 -> (after split x) x2H+x2L+gi
  char* regB = alloc((size_t)N * 512 * 4);
  float* x   = (float*)regB;
  short* x2H = (short*)regB;
  short* x2L = (short*)(regB + (size_t)N * 128 * 2);
  float* gi  = (float*)(regB + (size_t)N * 128 * 4);
  _Float16* zh  = (_Float16*)alloc((size_t)N * 512 * 2);  // fp16 gather plane
  _Float16* z2h = (_Float16*)alloc((size_t)N * 128 * 2);
  float* z2    = (float*)alloc((size_t)N * 128 * 4);
  short* hH    = (short*)alloc((size_t)N * 128 * 2);
  short* hL    = (short*)alloc((size_t)N * 128 * 2);
  float* asrc  = (float*)alloc((size_t)4 * N * 4);
  float* adst  = (float*)alloc((size_t)4 * N * 4);
  float* a2s   = (float*)alloc((size_t)N * 4);
  float* a2d   = (float*)alloc((size_t)N * 4);
  int* deg     = (int*)alloc((size_t)N * 4);
  int* ptr     = (int*)alloc((size_t)(N + 1) * 4);
  int* cursor  = (int*)alloc((size_t)N * 4);
  int* src_s   = (int*)alloc((size_t)E * 4);
  float* pd_s  = (float*)alloc((size_t)E * 4);
  short* fcWH  = (short*)alloc((size_t)512 * 128 * 2);
  short* fcWL  = (short*)alloc((size_t)512 * 128 * 2);
  short* ofcWH = (short*)alloc((size_t)128 * 512 * 2);
  short* ofcWL = (short*)alloc((size_t)128 * 512 * 2);
  short* WihH  = (short*)alloc((size_t)384 * 128 * 2);
  short* WihL  = (short*)alloc((size_t)384 * 128 * 2);
  short* WhhH  = (short*)alloc((size_t)384 * 128 * 2);
  short* WhhL  = (short*)alloc((size_t)384 * 128 * 2);
  float* x2 = out;
  (void)ws_size; (void)n_in; (void)out_size;

  const int nodeBlocks = (N + 3) / 4;
  const int eBlocks = (E + 255) / 256;
  const int mBlocks = (N + 127) / 128;

  // 0) split weights + h to bf16 hi/lo planes
  split_bf16_k<<<512, 256, 0, stream>>>(h, hH, hL, N * 128 / 4);
  split_bf16_k<<<64, 256, 0, stream>>>(fcW, fcWH, fcWL, 512 * 128 / 4);
  split_bf16_k<<<64, 256, 0, stream>>>(ofcW, ofcWH, ofcWL, 128 * 512 / 4);
  split_bf16_k<<<48, 256, 0, stream>>>(Wih, WihH, WihL, 384 * 128 / 4);
  split_bf16_k<<<48, 256, 0, stream>>>(Whh, WhhH, WhhL, 384 * 128 / 4);

  // 1) z = lrelu(h @ fcW^T) + fp16 copy zh
  gemm_bf16x3<128, true, false, true><<<dim3(512 / 128, mBlocks), 256, 0, stream>>>(
      hH, hL, fcWH, fcWL, nullptr, z, zh, N, 512, 128);

  // 2) per-head attention scalars
  attn_heads_k<<<nodeBlocks, 256, 0, stream>>>(z, attnW, asrc, adst, N);

  // 3) CSR over dst
  hipMemsetAsync(deg, 0, (size_t)N * 4, stream);
  hipMemsetAsync(cursor, 0, (size_t)N * 4, stream);
  hist_k<<<eBlocks, 256, 0, stream>>>(dst, deg, E);
  scan_k<<<1, 1024, 0, stream>>>(deg, ptr, N);
  scatter_k<<<eBlocks, 256, 0, stream>>>(dst, src, pd, ptr, cursor, src_s, pd_s, E);

  // 4) FUSED 4-head aggregation -> x  (z/zh dead after this)
  gat_heads_fused<<<nodeBlocks, 256, 0, stream>>>(
      zh, asrc, adst, pd_s, edgew, mw, src_s, ptr, x, N);

  // 4b) split x -> xH/xL (overwrites dead z region)
  split_bf16_k<<<2048, 256, 0, stream>>>(x, xH, xL, N * 512 / 4);

  // 5) z2 = lrelu(x @ ofcW^T) + fp16 copy z2h
  gemm_bf16x3<64, true, false, true><<<dim3(128 / 64, mBlocks), 256, 0, stream>>>(
      xH, xL, ofcWH, ofcWL, nullptr, z2, z2h, N, 128, 512);

  // 6) out-layer attention scalars
  attn_out_k<<<nodeBlocks, 256, 0, stream>>>(z2, oattn, a2s, a2d, N);

  // 7) out-layer aggregation -> x2 (in d_out)
  gat_out_aggregate<<<nodeBlocks, 256, 0, stream>>>(
      z2h, a2s, a2d, pd_s, oew, omw, src_s, ptr, x2, N);

  // 7b) split x2 -> x2H/x2L (into dead x region)
  split_bf16_k<<<512, 256, 0, stream>>>(x2, x2H, x2L, N * 128 / 4);

  // 8) GRU GEMMs
  gemm_bf16x3<64, false, true, false><<<dim3(384 / 64, mBlocks), 256, 0, stream>>>(
      x2H, x2L, WihH, WihL, bih, gi, nullptr, N, 384, 128);
  gemm_bf16x3<64, false, true, false><<<dim3(384 / 64, mBlocks), 256, 0, stream>>>(
      hH, hL, WhhH, WhhL, bhh, gh, nullptr, N, 384, 128);

  // 9) gates + final lrelu -> d_out
  gru_gate_k<<<(N * 128 + 255) / 256, 256, 0, stream>>>(gi, gh, h, out, N * 128);
}

// Round 12
// 558.442 us; speedup vs baseline: 1.3081x; 1.0967x over previous
//
#include <hip/hip_runtime.h>
#include <math.h>

#define NEG_SLOPE 0.01f

__device__ __forceinline__ float lrelu_f(float x) { return x >= 0.f ? x : NEG_SLOPE * x; }

typedef __attribute__((ext_vector_type(8))) short short8v;
typedef __attribute__((ext_vector_type(4))) short short4v;
typedef __attribute__((ext_vector_type(4))) float f32x4;
typedef __attribute__((ext_vector_type(8))) _Float16 half8v;
typedef __attribute__((ext_vector_type(4))) _Float16 half4v;

__device__ __forceinline__ unsigned short f2bf(float f) {  // fp32 -> bf16 RNE
  unsigned u = __float_as_uint(f);
  u += 0x7FFF + ((u >> 16) & 1);
  return (unsigned short)(u >> 16);
}
__device__ __forceinline__ float bf2f(unsigned short s) {
  return __uint_as_float((unsigned)s << 16);
}

// ---------------------------------------------------------------------------
// Split fp32 -> planar bf16 (hi) + bf16 (lo residual). Grid-stride, float4.
// (Only used for inputs h and the 4 weight matrices now.)
// ---------------------------------------------------------------------------
__global__ __launch_bounds__(256)
void split_bf16_k(const float* __restrict__ in, short* __restrict__ H,
                  short* __restrict__ L, int n4) {
  const int stride = gridDim.x * 256;
  for (int i = blockIdx.x * 256 + threadIdx.x; i < n4; i += stride) {
    const float4 v = ((const float4*)in)[i];
    short4v h, l;
    h[0] = (short)f2bf(v.x); l[0] = (short)f2bf(v.x - bf2f(h[0]));
    h[1] = (short)f2bf(v.y); l[1] = (short)f2bf(v.y - bf2f(h[1]));
    h[2] = (short)f2bf(v.z); l[2] = (short)f2bf(v.z - bf2f(h[2]));
    h[3] = (short)f2bf(v.w); l[3] = (short)f2bf(v.w - bf2f(h[3]));
    ((short4v*)H)[i] = h;
    ((short4v*)L)[i] = l;
  }
}

// ---------------------------------------------------------------------------
// GEMM via bf16x3 MFMA on PRE-SPLIT planar bf16 inputs (r7-validated core).
// COUT: write fp32 C. HOUT: write fp16 copy. (GEMM1/2: HOUT only; GRU: COUT.)
// ---------------------------------------------------------------------------
template<int TN, bool LRELU, bool BIAS, bool COUT, bool HOUT>
__global__ __launch_bounds__(256)
void gemm_bf16x3(const short* __restrict__ AH, const short* __restrict__ AL,
                 const short* __restrict__ BH, const short* __restrict__ BL,
                 const float* __restrict__ bias, float* __restrict__ C,
                 _Float16* __restrict__ Ch, int M, int Nn, int K) {
  constexpr int MI = (TN == 128) ? 4 : 2;
  constexpr int NI = 4;
  __shared__ short AsH[128 * 64], AsL[128 * 64];
  __shared__ short BsH[TN * 64],  BsL[TN * 64];
  const int tid = threadIdx.x;
  const int lane = tid & 63, w = tid >> 6;
  const int tx = tid & 15, ty = tid >> 4;
  const int bm = blockIdx.y << 7, bn = blockIdx.x * TN;
  const int m0 = (TN == 128) ? (w >> 1) * 64 : w * 32;
  const int n0 = (TN == 128) ? (w & 1) * 64 : 0;
  const int sbase = (tx >> 3) * 32 + (tx & 3) * 8 + ((tx >> 2) & 1) * 4;
  const int g = lane >> 4;
  const int key = (lane & 7) << 3;
  const int arow = lane & 15;

  f32x4 acc[MI][NI];
#pragma unroll
  for (int i = 0; i < MI; ++i)
#pragma unroll
    for (int j = 0; j < NI; ++j) acc[i][j] = (f32x4){0.f, 0.f, 0.f, 0.f};

  for (int k0 = 0; k0 < K; k0 += 64) {
#pragma unroll
    for (int i = 0; i < 8; ++i) {           // stage A: 128 rows x 64 k
      const int r = ty + (i << 4);
      int ar = bm + r; ar = ar < M ? ar : M - 1;
      const size_t go = (size_t)ar * K + k0 + (tx << 2);
      const short4v h = *(const short4v*)(AH + go);
      const short4v l = *(const short4v*)(AL + go);
      const int idx = r * 64 + (sbase ^ ((r & 7) << 3));
      *(short4v*)&AsH[idx] = h;
      *(short4v*)&AsL[idx] = l;
    }
#pragma unroll
    for (int i = 0; i < TN / 16; ++i) {     // stage B: TN rows x 64 k
      const int r = ty + (i << 4);
      const size_t go = (size_t)(bn + r) * K + k0 + (tx << 2);
      const short4v h = *(const short4v*)(BH + go);
      const short4v l = *(const short4v*)(BL + go);
      const int idx = r * 64 + (sbase ^ ((r & 7) << 3));
      *(short4v*)&BsH[idx] = h;
      *(short4v*)&BsL[idx] = l;
    }
    __syncthreads();
#pragma unroll
    for (int kh = 0; kh < 2; ++kh) {        // two K=32 MFMA steps per chunk
      const int sb = kh * 32 + g * 8;
      short8v aH[MI], aL[MI], bH[NI], bL[NI];
#pragma unroll
      for (int mi = 0; mi < MI; ++mi) {
        const int base = (m0 + arow + mi * 16) * 64 + (sb ^ key);
        aH[mi] = *(const short8v*)&AsH[base];
        aL[mi] = *(const short8v*)&AsL[base];
      }
#pragma unroll
      for (int ni = 0; ni < NI; ++ni) {
        const int base = (n0 + arow + ni * 16) * 64 + (sb ^ key);
        bH[ni] = *(const short8v*)&BsH[base];
        bL[ni] = *(const short8v*)&BsL[base];
      }
#pragma unroll
      for (int mi = 0; mi < MI; ++mi)
#pragma unroll
        for (int ni = 0; ni < NI; ++ni) {
          acc[mi][ni] = __builtin_amdgcn_mfma_f32_16x16x32_bf16(aH[mi], bH[ni], acc[mi][ni], 0, 0, 0);
          acc[mi][ni] = __builtin_amdgcn_mfma_f32_16x16x32_bf16(aH[mi], bL[ni], acc[mi][ni], 0, 0, 0);
          acc[mi][ni] = __builtin_amdgcn_mfma_f32_16x16x32_bf16(aL[mi], bH[ni], acc[mi][ni], 0, 0, 0);
        }
    }
    __syncthreads();
  }

  const int rg = (lane >> 4) << 2;
#pragma unroll
  for (int ni = 0; ni < NI; ++ni) {
    const int col = bn + n0 + ni * 16 + (lane & 15);
    const float bc = BIAS ? bias[col] : 0.f;
#pragma unroll
    for (int mi = 0; mi < MI; ++mi) {
#pragma unroll
      for (int r4 = 0; r4 < 4; ++r4) {
        const int row = bm + m0 + mi * 16 + rg + r4;
        if (row < M) {
          float v = acc[mi][ni][r4] + bc;
          if (LRELU) v = lrelu_f(v);
          if (COUT) C[(size_t)row * Nn + col] = v;
          if (HOUT) Ch[(size_t)row * Nn + col] = (_Float16)v;
        }
      }
    }
  }
}

// ---------------------------------------------------------------------------
// a_src/a_dst for the 4 heads from fp16 z. One wave per node.
// ---------------------------------------------------------------------------
__global__ __launch_bounds__(256)
void attn_heads_k(const _Float16* __restrict__ zh, const float* __restrict__ attnW,
                  float* __restrict__ asrc, float* __restrict__ adst, int N) {
  const int wid = (int)((blockIdx.x * (unsigned)blockDim.x + threadIdx.x) >> 6);
  const int lane = threadIdx.x & 63;
  if (wid >= N) return;
  const int h = lane >> 4;
  const int dd = (lane & 15) << 3;
  const _Float16* zp = zh + (size_t)wid * 512 + h * 128 + dd;
  const float* aw = attnW + h * 256 + dd;
  const half8v zv = *(const half8v*)zp;
  const float4 w0 = *(const float4*)aw;
  const float4 w1 = *(const float4*)(aw + 4);
  const float4 w2 = *(const float4*)(aw + 128);
  const float4 w3 = *(const float4*)(aw + 132);
  float ps = (float)zv[0] * w0.x + (float)zv[1] * w0.y + (float)zv[2] * w0.z + (float)zv[3] * w0.w
           + (float)zv[4] * w1.x + (float)zv[5] * w1.y + (float)zv[6] * w1.z + (float)zv[7] * w1.w;
  float pq = (float)zv[0] * w2.x + (float)zv[1] * w2.y + (float)zv[2] * w2.z + (float)zv[3] * w2.w
           + (float)zv[4] * w3.x + (float)zv[5] * w3.y + (float)zv[6] * w3.z + (float)zv[7] * w3.w;
#pragma unroll
  for (int off = 8; off; off >>= 1) {
    ps += __shfl_xor(ps, off);
    pq += __shfl_xor(pq, off);
  }
  if ((lane & 15) == 0) {
    asrc[(size_t)h * N + wid] = ps;
    adst[(size_t)h * N + wid] = pq;
  }
}

// a_src/a_dst for the output layer from fp16 z2. One wave/node.
__global__ __launch_bounds__(256)
void attn_out_k(const _Float16* __restrict__ z2h, const float* __restrict__ attnW,
                float* __restrict__ asrc, float* __restrict__ adst, int N) {
  const int wid = (int)((blockIdx.x * (unsigned)blockDim.x + threadIdx.x) >> 6);
  const int lane = threadIdx.x & 63;
  if (wid >= N) return;
  const _Float16* zp = z2h + (size_t)wid * 128;
  const float za = (float)zp[lane], zb = (float)zp[lane + 64];
  float ps = za * attnW[lane] + zb * attnW[lane + 64];
  float pq = za * attnW[128 + lane] + zb * attnW[192 + lane];
#pragma unroll
  for (int off = 32; off; off >>= 1) {
    ps += __shfl_xor(ps, off);
    pq += __shfl_xor(pq, off);
  }
  if (lane == 0) {
    asrc[wid] = ps;
    adst[wid] = pq;
  }
}

// ---------------------------------------------------------------------------
// CSR build over dst (scatter materializes dst-sorted src/pd).
// ---------------------------------------------------------------------------
__global__ void hist_k(const int* __restrict__ dst, int* __restrict__ deg, int E) {
  const int i = blockIdx.x * 256 + threadIdx.x;
  if (i < E) atomicAdd(&deg[dst[i]], 1);
}

__global__ __launch_bounds__(1024)
void scan_k(const int* __restrict__ deg, int* __restrict__ ptr, int n) {
  __shared__ int wsum[16];
  __shared__ int carry_s;
  const int tid = threadIdx.x;
  const int lane = tid & 63, wv = tid >> 6;
  if (tid == 0) carry_s = 0;
  __syncthreads();
  for (int base = 0; base < n; base += 1024) {
    const int i = base + tid;
    int s = (i < n) ? deg[i] : 0;
#pragma unroll
    for (int off = 1; off < 64; off <<= 1) {
      const int t = __shfl_up(s, off);
      if (lane >= off) s += t;
    }
    if (lane == 63) wsum[wv] = s;
    __syncthreads();
    if (wv == 0 && lane < 16) {
      int ws = wsum[lane];
#pragma unroll
      for (int off = 1; off < 16; off <<= 1) {
        const int t = __shfl_up(ws, off);
        if (lane >= off) ws += t;
      }
      wsum[lane] = ws;
    }
    __syncthreads();
    const int wprefix = (wv == 0) ? 0 : wsum[wv - 1];
    const int carry = carry_s;
    if (i < n) ptr[i + 1] = carry + wprefix + s;
    __syncthreads();
    if (tid == 1023) carry_s = carry + wsum[15];
    __syncthreads();
  }
  if (tid == 0) ptr[0] = 0;
}

__global__ void scatter_k(const int* __restrict__ dst, const int* __restrict__ src,
                          const float* __restrict__ pd, const int* __restrict__ ptr,
                          int* __restrict__ cursor,
                          int* __restrict__ src_s, float* __restrict__ pd_s, int E) {
  const int i = blockIdx.x * 256 + threadIdx.x;
  if (i < E) {
    const int d = dst[i];
    const int p = ptr[d] + atomicAdd(&cursor[d], 1);
    src_s[p] = src[i];
    pd_s[p] = pd[i];
  }
}

// ---------------------------------------------------------------------------
// FUSED 4-head segment softmax + aggregation. One wave per dst node.
// Pass B: lane owns 8 cols of head lane>>4; 1x16B fp16 gather per edge,
// 4 edges in flight. Output written DIRECTLY as bf16 hi/lo planes (fused
// split for the next GEMM) — no fp32 x, no separate split pass.
// ---------------------------------------------------------------------------
__global__ __launch_bounds__(256)
void gat_heads_fused(const _Float16* __restrict__ zh,
                     const float* __restrict__ asrc, const float* __restrict__ adst,
                     const float* __restrict__ pd_s,
                     const float* __restrict__ ewp, const float* __restrict__ mwp,
                     const int* __restrict__ src_s, const int* __restrict__ csr_ptr,
                     short* __restrict__ xH, short* __restrict__ xL, int N) {
  __shared__ float pair[4][128][5];   // [wave][slot][(ex0..ex3, src)]
  const int wib = threadIdx.x >> 6;
  const int wid = blockIdx.x * 4 + wib;
  const int lane = threadIdx.x & 63;
  if (wid >= N) return;
  const int rs = csr_ptr[wid], re = csr_ptr[wid + 1];
  const int deg = re - rs;
  const int hh = lane >> 4;           // head owned in pass B
  const int c = lane << 3;            // 8 cols owned
  short* opH = xH + (size_t)wid * 512 + c;
  short* opL = xL + (size_t)wid * 512 + c;
  if (deg == 0) {
    short8v zv = {0, 0, 0, 0, 0, 0, 0, 0};
    *(short8v*)opH = zv;
    *(short8v*)opL = zv;
    return;
  }
  float ew[4], mwv[4], adn[4];
#pragma unroll
  for (int h = 0; h < 4; ++h) {
    ew[h] = ewp[h]; mwv[h] = mwp[h];
    adn[h] = adst[(size_t)h * N + wid];
  }
  const int j0 = rs + lane, j1 = j0 + 64;
  const bool v0 = j0 < re, v1 = j1 < re;
  const int s0 = v0 ? src_s[j0] : 0;
  const float p0 = v0 ? pd_s[j0] : 0.f;
  const int s1 = v1 ? src_s[j1] : 0;
  const float p1 = v1 ? pd_s[j1] : 0.f;
  float ne0[4], ne1[4], m[4];
#pragma unroll
  for (int h = 0; h < 4; ++h) {
    const float a0 = asrc[(size_t)h * N + s0];
    const float a1 = asrc[(size_t)h * N + s1];
    ne0[h] = v0 ? mwv[h] * lrelu_f((a0 + adn[h]) * (p0 * ew[h])) : -INFINITY;
    ne1[h] = v1 ? mwv[h] * lrelu_f((a1 + adn[h]) * (p1 * ew[h])) : -INFINITY;
    m[h] = fmaxf(ne0[h], ne1[h]);
  }
  for (int j = rs + 128 + lane; j < re; j += 64) {  // statistically never
    const int s = src_s[j];
    const float p = pd_s[j];
#pragma unroll
    for (int h = 0; h < 4; ++h)
      m[h] = fmaxf(m[h], mwv[h] * lrelu_f((asrc[(size_t)h * N + s] + adn[h]) * (p * ew[h])));
  }
#pragma unroll
  for (int h = 0; h < 4; ++h)
#pragma unroll
    for (int off = 32; off; off >>= 1) m[h] = fmaxf(m[h], __shfl_xor(m[h], off));

  float ss[4];
#pragma unroll
  for (int h = 0; h < 4; ++h) {
    const float e0 = expf(ne0[h] - m[h]);   // -INF -> 0
    const float e1 = expf(ne1[h] - m[h]);
    pair[wib][lane][h] = e0;
    pair[wib][lane + 64][h] = e1;
    ss[h] = e0 + e1;
  }
  pair[wib][lane][4] = __int_as_float(s0);
  pair[wib][lane + 64][4] = __int_as_float(s1);
  for (int j = rs + 128 + lane; j < re; j += 64) {  // tail into ss only
    const int s = src_s[j];
    const float p = pd_s[j];
#pragma unroll
    for (int h = 0; h < 4; ++h)
      ss[h] += expf(mwv[h] * lrelu_f((asrc[(size_t)h * N + s] + adn[h]) * (p * ew[h])) - m[h]);
  }
#pragma unroll
  for (int h = 0; h < 4; ++h)
#pragma unroll
    for (int off = 32; off; off >>= 1) ss[h] += __shfl_xor(ss[h], off);

  // ---- pass B: 4 edges in flight, 1x16B fp16 gather each ----
  float a[8] = {0.f, 0.f, 0.f, 0.f, 0.f, 0.f, 0.f, 0.f};
  for (int q0 = 0; q0 < deg; q0 += 4) {
    float exv[4]; int sv[4];
#pragma unroll
    for (int u = 0; u < 4; ++u) {
      const int q = q0 + u;
      if (q < deg) {
        if (q < 128) {
          exv[u] = pair[wib][q][hh];
          sv[u] = __float_as_int(pair[wib][q][4]);
        } else {                    // rare tail: recompute for own head
          sv[u] = src_s[rs + q];
          exv[u] = expf(mwv[hh] * lrelu_f((asrc[(size_t)hh * N + sv[u]] + adn[hh]) * (pd_s[rs + q] * ew[hh])) - m[hh]);
        }
      } else {
        exv[u] = 0.f; sv[u] = 0;
      }
    }
    half8v zv[4];
#pragma unroll
    for (int u = 0; u < 4; ++u)
      zv[u] = *(const half8v*)(zh + (size_t)sv[u] * 512 + c);
#pragma unroll
    for (int u = 0; u < 4; ++u)
#pragma unroll
      for (int t = 0; t < 8; ++t) a[t] = fmaf(exv[u], (float)zv[u][t], a[t]);
  }
  const float rd = 1.f / ((ss[hh] > 0.f) ? ss[hh] : 1.f);
  short8v hv, lv;
#pragma unroll
  for (int t = 0; t < 8; ++t) {
    const float v = lrelu_f(a[t] * rd);
    hv[t] = (short)f2bf(v);
    lv[t] = (short)f2bf(v - bf2f((unsigned short)hv[t]));
  }
  *(short8v*)opH = hv;
  *(short8v*)opL = lv;
}

// ---------------------------------------------------------------------------
// Out-layer segment softmax + aggregation (fp16 z2 gather); writes bf16
// hi/lo planes directly (fused split for the GRU gi GEMM).
// ---------------------------------------------------------------------------
__global__ __launch_bounds__(256)
void gat_out_aggregate(const _Float16* __restrict__ zh,
                       const float* __restrict__ asrc, const float* __restrict__ adst,
                       const float* __restrict__ pd_s,
                       const float* __restrict__ ewp, const float* __restrict__ mwp,
                       const int* __restrict__ src_s, const int* __restrict__ csr_ptr,
                       short* __restrict__ x2H, short* __restrict__ x2L, int N) {
  __shared__ float pair[4][128][2];
  const int wib = threadIdx.x >> 6;
  const int wid = blockIdx.x * 4 + wib;
  const int lane = threadIdx.x & 63;
  if (wid >= N) return;
  const int rs = csr_ptr[wid], re = csr_ptr[wid + 1];
  const int deg = re - rs;
  const int l32 = lane & 31;
  const int half = lane >> 5;
  const int zoff = l32 << 2;
  short* opH = x2H + (size_t)wid * 128 + zoff;
  short* opL = x2L + (size_t)wid * 128 + zoff;
  if (deg == 0) {
    if (half == 0) {
      short4v zv = {0, 0, 0, 0};
      *(short4v*)opH = zv;
      *(short4v*)opL = zv;
    }
    return;
  }
  const float ew = ewp[0];
  const float mw = mwp[0];
  const float adn = adst[wid];

  float ne0 = -INFINITY, ne1 = -INFINITY;
  int s0 = 0, s1 = 0;
  {
    int j = rs + lane;
    if (j < re) {
      s0 = src_s[j];
      ne0 = mw * lrelu_f((asrc[s0] + adn) * (pd_s[j] * ew));
    }
    j += 64;
    if (j < re) {
      s1 = src_s[j];
      ne1 = mw * lrelu_f((asrc[s1] + adn) * (pd_s[j] * ew));
    }
  }
  float m = fmaxf(ne0, ne1);
  for (int j = rs + 128 + lane; j < re; j += 64) {
    const int s = src_s[j];
    m = fmaxf(m, mw * lrelu_f((asrc[s] + adn) * (pd_s[j] * ew)));
  }
#pragma unroll
  for (int off = 32; off; off >>= 1) m = fmaxf(m, __shfl_xor(m, off));

  const float ex0 = expf(ne0 - m);
  const float ex1 = expf(ne1 - m);
  float ss = ex0 + ex1;
  for (int j = rs + 128 + lane; j < re; j += 64) {
    const int s = src_s[j];
    ss += expf(mw * lrelu_f((asrc[s] + adn) * (pd_s[j] * ew)) - m);
  }
#pragma unroll
  for (int off = 32; off; off >>= 1) ss += __shfl_xor(ss, off);

  pair[wib][lane][0] = ex0;
  pair[wib][lane][1] = __int_as_float(s0);
  pair[wib][lane + 64][0] = ex1;
  pair[wib][lane + 64][1] = __int_as_float(s1);

  float a0 = 0.f, a1 = 0.f, a2 = 0.f, a3 = 0.f;
  for (int q0 = 0; q0 < deg; q0 += 8) {
#pragma unroll
    for (int u = 0; u < 4; ++u) {
      const int q = q0 + (u << 1) + half;
      float exv; int sv;
      if (q < deg) {
        if (q < 128) {
          const float2 p = *(const float2*)&pair[wib][q][0];
          exv = p.x; sv = __float_as_int(p.y);
        } else {
          sv = src_s[rs + q];
          exv = expf(mw * lrelu_f((asrc[sv] + adn) * (pd_s[rs + q] * ew)) - m);
        }
      } else {
        exv = 0.f; sv = 0;
      }
      const half4v zv = *(const half4v*)(zh + (size_t)sv * 128 + zoff);
      a0 = fmaf(exv, (float)zv[0], a0);
      a1 = fmaf(exv, (float)zv[1], a1);
      a2 = fmaf(exv, (float)zv[2], a2);
      a3 = fmaf(exv, (float)zv[3], a3);
    }
  }
  a0 += __shfl_xor(a0, 32);
  a1 += __shfl_xor(a1, 32);
  a2 += __shfl_xor(a2, 32);
  a3 += __shfl_xor(a3, 32);
  if (half == 0) {
    const float rd = 1.f / ((ss > 0.f) ? ss : 1.f);
    float v[4] = {lrelu_f(a0 * rd), lrelu_f(a1 * rd), lrelu_f(a2 * rd), lrelu_f(a3 * rd)};
    short4v hv, lv;
#pragma unroll
    for (int t = 0; t < 4; ++t) {
      hv[t] = (short)f2bf(v[t]);
      lv[t] = (short)f2bf(v[t] - bf2f((unsigned short)hv[t]));
    }
    *(short4v*)opH = hv;
    *(short4v*)opL = lv;
  }
}

// ---------------------------------------------------------------------------
// GRU gates + final lrelu.
// ---------------------------------------------------------------------------
__global__ __launch_bounds__(256)
void gru_gate_k(const float* __restrict__ gi, const float* __restrict__ gh,
                const float* __restrict__ h, float* __restrict__ out, int total) {
  const int i = blockIdx.x * 256 + threadIdx.x;
  if (i >= total) return;
  const int n = i >> 7, d = i & 127;
  const float* gin = gi + (size_t)n * 384;
  const float* ghn = gh + (size_t)n * 384;
  const float r = 1.f / (1.f + expf(-(gin[d] + ghn[d])));
  const float zg = 1.f / (1.f + expf(-(gin[128 + d] + ghn[128 + d])));
  const float ng = tanhf(gin[256 + d] + r * ghn[256 + d]);
  const float v = (1.f - zg) * ng + zg * h[i];
  out[i] = lrelu_f(v);
}

// ---------------------------------------------------------------------------
extern "C" void kernel_launch(void* const* d_in, const int* in_sizes, int n_in,
                              void* d_out, int out_size, void* d_ws, size_t ws_size,
                              hipStream_t stream) {
  const int N = in_sizes[0] / 128;
  const int E = in_sizes[1];

  const float* h     = (const float*)d_in[0];
  const float* pd    = (const float*)d_in[1];
  const int*   src   = (const int*)d_in[2];
  const int*   dst   = (const int*)d_in[3];
  const float* fcW   = (const float*)d_in[4];
  const float* attnW = (const float*)d_in[5];
  const float* edgew = (const float*)d_in[6];
  const float* mw    = (const float*)d_in[7];
  const float* ofcW  = (const float*)d_in[8];
  const float* oattn = (const float*)d_in[9];
  const float* oew   = (const float*)d_in[10];
  const float* omw   = (const float*)d_in[11];
  const float* Wih   = (const float*)d_in[12];
  const float* Whh   = (const float*)d_in[13];
  const float* bih   = (const float*)d_in[14];
  const float* bhh   = (const float*)d_in[15];
  float* out = (float*)d_out;

  char* w = (char*)d_ws;
  size_t off = 0;
  auto alloc = [&](size_t bytes) -> char* {
    char* p = w + off;
    off += (bytes + 255) & ~(size_t)255;
    return p;
  };
  // Region A: xH+xL (heads-agg bf16 planes) -> (after GEMM2 consumes) gh fp32
  char* regA = alloc((size_t)N * 512 * 4);
  short* xH  = (short*)regA;                              // N*512 bf16
  short* xL  = (short*)(regA + (size_t)N * 512 * 2);
  float* gh  = (float*)regA;                              // N*384 fp32
  // Region B: x2H+x2L (out-agg bf16 planes) + gi fp32
  char* regB = alloc((size_t)N * 512 * 4);
  short* x2H = (short*)regB;                              // N*128 bf16
  short* x2L = (short*)(regB + (size_t)N * 128 * 2);
  float* gi  = (float*)(regB + (size_t)N * 128 * 4);      // N*384 fp32
  _Float16* zh  = (_Float16*)alloc((size_t)N * 512 * 2);  // fp16 gather plane
  _Float16* z2h = (_Float16*)alloc((size_t)N * 128 * 2);
  short* hH    = (short*)alloc((size_t)N * 128 * 2);
  short* hL    = (short*)alloc((size_t)N * 128 * 2);
  float* asrc  = (float*)alloc((size_t)4 * N * 4);
  float* adst  = (float*)alloc((size_t)4 * N * 4);
  float* a2s   = (float*)alloc((size_t)N * 4);
  float* a2d   = (float*)alloc((size_t)N * 4);
  int* deg     = (int*)alloc((size_t)N * 4);
  int* ptr     = (int*)alloc((size_t)(N + 1) * 4);
  int* cursor  = (int*)alloc((size_t)N * 4);
  int* src_s   = (int*)alloc((size_t)E * 4);
  float* pd_s  = (float*)alloc((size_t)E * 4);
  short* fcWH  = (short*)alloc((size_t)512 * 128 * 2);
  short* fcWL  = (short*)alloc((size_t)512 * 128 * 2);
  short* ofcWH = (short*)alloc((size_t)128 * 512 * 2);
  short* ofcWL = (short*)alloc((size_t)128 * 512 * 2);
  short* WihH  = (short*)alloc((size_t)384 * 128 * 2);
  short* WihL  = (short*)alloc((size_t)384 * 128 * 2);
  short* WhhH  = (short*)alloc((size_t)384 * 128 * 2);
  short* WhhL  = (short*)alloc((size_t)384 * 128 * 2);
  (void)ws_size; (void)n_in; (void)out_size;

  const int nodeBlocks = (N + 3) / 4;
  const int eBlocks = (E + 255) / 256;
  const int mBlocks = (N + 127) / 128;

  // 0) split weights + h to bf16 hi/lo planes
  split_bf16_k<<<512, 256, 0, stream>>>(h, hH, hL, N * 128 / 4);
  split_bf16_k<<<64, 256, 0, stream>>>(fcW, fcWH, fcWL, 512 * 128 / 4);
  split_bf16_k<<<64, 256, 0, stream>>>(ofcW, ofcWH, ofcWL, 128 * 512 / 4);
  split_bf16_k<<<48, 256, 0, stream>>>(Wih, WihH, WihL, 384 * 128 / 4);
  split_bf16_k<<<48, 256, 0, stream>>>(Whh, WhhH, WhhL, 384 * 128 / 4);

  // 1) zh = fp16( lrelu(h @ fcW^T) )  — no fp32 plane
  gemm_bf16x3<128, true, false, false, true><<<dim3(512 / 128, mBlocks), 256, 0, stream>>>(
      hH, hL, fcWH, fcWL, nullptr, nullptr, zh, N, 512, 128);

  // 2) per-head attention scalars (from fp16 z)
  attn_heads_k<<<nodeBlocks, 256, 0, stream>>>(zh, attnW, asrc, adst, N);

  // 3) CSR over dst
  hipMemsetAsync(deg, 0, (size_t)N * 4, stream);
  hipMemsetAsync(cursor, 0, (size_t)N * 4, stream);
  hist_k<<<eBlocks, 256, 0, stream>>>(dst, deg, E);
  scan_k<<<1, 1024, 0, stream>>>(deg, ptr, N);
  scatter_k<<<eBlocks, 256, 0, stream>>>(dst, src, pd, ptr, cursor, src_s, pd_s, E);

  // 4) FUSED 4-head aggregation -> xH/xL bf16 planes directly
  gat_heads_fused<<<nodeBlocks, 256, 0, stream>>>(
      zh, asrc, adst, pd_s, edgew, mw, src_s, ptr, xH, xL, N);

  // 5) z2h = fp16( lrelu(x @ ofcW^T) )
  gemm_bf16x3<64, true, false, false, true><<<dim3(128 / 64, mBlocks), 256, 0, stream>>>(
      xH, xL, ofcWH, ofcWL, nullptr, nullptr, z2h, N, 128, 512);

  // 6) out-layer attention scalars (from fp16 z2)
  attn_out_k<<<nodeBlocks, 256, 0, stream>>>(z2h, oattn, a2s, a2d, N);

  // 7) out-layer aggregation -> x2H/x2L bf16 planes directly
  gat_out_aggregate<<<nodeBlocks, 256, 0, stream>>>(
      z2h, a2s, a2d, pd_s, oew, omw, src_s, ptr, x2H, x2L, N);

  // 8) GRU GEMMs (fp32 out)
  gemm_bf16x3<64, false, true, true, false><<<dim3(384 / 64, mBlocks), 256, 0, stream>>>(
      x2H, x2L, WihH, WihL, bih, gi, nullptr, N, 384, 128);
  gemm_bf16x3<64, false, true, true, false><<<dim3(384 / 64, mBlocks), 256, 0, stream>>>(
      hH, hL, WhhH, WhhL, bhh, gh, nullptr, N, 384, 128);

  // 9) gates + final lrelu -> d_out
  gru_gate_k<<<(N * 128 + 255) / 256, 256, 0, stream>>>(gi, gh, h, out, N * 128);
}